// Round 4
// baseline (1139.575 us; speedup 1.0000x reference)
//
#include <hip/hip_runtime.h>
#include <hip/hip_bf16.h>

typedef __hip_bfloat16 bf16;

#define NB   2
#define NPT  2048
#define NROI 128
#define CINF 256
#define NS   16
#define KDIM 259     // CIN + 3
#define KP   272     // KDIM padded to multiple of 4 (float4)
#define C1   256     // mlp out channels
#define C2   128     // layer1/2 out channels
#define NVOX 125
#define EPSF 1e-5f

__device__ __forceinline__ float b2f(bf16 x) { return __bfloat162float(x); }

// flag-branched input load: inputs are either all-bf16 or all-f32
__device__ __forceinline__ float ldin(const void* p, size_t i, int f32flag) {
    if (f32flag) return ((const float*)p)[i];
    unsigned short u = ((const unsigned short*)p)[i];
    return __uint_as_float(((unsigned)u) << 16);
}

// explicit round-to-nearest-even f32 -> bf16 (matches numpy)
__device__ __forceinline__ unsigned short f2bf(float x) {
    unsigned u = __float_as_uint(x);
    u += 0x7FFFu + ((u >> 16) & 1u);
    return (unsigned short)(u >> 16);
}

// ---------------- ws layout (float units) ----------------
// flag   @ 0        (16 floats reserved; flag int at [0])
// ptsf   @ 16       12288
// roisf  @ 12304    1792
// params @ 14096    50432  [gm 0 | btm 256 | W1 512 | b1 33280 | g1 33408 |
//                           bt1 33536 | W2 33664 | b2 50048 | g2 50176 | bt2 50304]
// Wp     @ 64528    69632  (C1*KP, f32, zero-padded)
// stats  @ 134160   1024   [sum0 0 | sq0 256 | sum1 512 | sq1 640 | sum2 768 | sq2 896]
// idxb   @ 135184   65536 ints
// ft     @ 200720   1048576  --> reused as f0 after k_mlp
// Hmax   @ 1249296  1048576  --> reused as h1|x1 after k_feats0
// Hmin   @ 2297872  1048576  --> reused as h2|fp after k_feats0
// total 3,346,448 floats = 13.4 MB

// D0: detect input dtype. True-bf16 W_mlp has |w| <= ~0.2; f32 misread as bf16
// yields |v|>1e4 or NaN among 1024 halves with certainty.
__global__ void k_detect(const void* __restrict__ Wm, int* __restrict__ flag) {
    __shared__ int f;
    int tid = threadIdx.x;
    if (tid == 0) f = 0;
    __syncthreads();
    #pragma unroll
    for (int r = 0; r < 4; r++) {
        unsigned short u = ((const unsigned short*)Wm)[r * 256 + tid];
        float v = __uint_as_float(((unsigned)u) << 16);
        if (!(fabsf(v) <= 1e4f)) atomicOr(&f, 1);   // catches huge AND NaN
    }
    __syncthreads();
    if (tid == 0) *flag = f;
}

// D1: convert pts/rois/all params to f32 scratch. blockIdx.y selects tensor.
__global__ void k_cvt(const void* __restrict__ pts, const void* __restrict__ rois,
                      const void* __restrict__ gm, const void* __restrict__ btm,
                      const void* __restrict__ W1, const void* __restrict__ b1,
                      const void* __restrict__ g1, const void* __restrict__ bt1,
                      const void* __restrict__ W2, const void* __restrict__ b2,
                      const void* __restrict__ g2, const void* __restrict__ bt2,
                      float* __restrict__ ptsf, float* __restrict__ roisf,
                      float* __restrict__ params, const int* __restrict__ flag) {
    int f = *flag;
    int e = blockIdx.x * 256 + threadIdx.x;
    const void* src; float* dst; int n;
    switch (blockIdx.y) {
        case 0:  src = pts; dst = ptsf;           n = NB * NPT * 3; break;
        case 1:  src = rois; dst = roisf;         n = NB * NROI * 7; break;
        case 2:  src = gm;  dst = params + 0;     n = 256; break;
        case 3:  src = btm; dst = params + 256;   n = 256; break;
        case 4:  src = W1;  dst = params + 512;   n = 32768; break;
        case 5:  src = b1;  dst = params + 33280; n = 128; break;
        case 6:  src = g1;  dst = params + 33408; n = 128; break;
        case 7:  src = bt1; dst = params + 33536; n = 128; break;
        case 8:  src = W2;  dst = params + 33664; n = 16384; break;
        case 9:  src = b2;  dst = params + 50048; n = 128; break;
        case 10: src = g2;  dst = params + 50176; n = 128; break;
        default: src = bt2; dst = params + 50304; n = 128; break;
    }
    if (e < n) dst[e] = ldin(src, e, f);
}

// K0a: transpose features (B,CIN,N) -> ft (B,N,CIN) f32
__global__ void k_transpose(const void* __restrict__ feat, float* __restrict__ ft,
                            const int* __restrict__ flag) {
    __shared__ float tile[32][33];
    int f = *flag;
    int b = blockIdx.z;
    int n0 = blockIdx.x * 32, c0 = blockIdx.y * 32;
    int tx = threadIdx.x, ty = threadIdx.y;  // 32x8
    #pragma unroll
    for (int d = 0; d < 4; d++) {
        int c = c0 + ty + d * 8;
        tile[ty + d * 8][tx] = ldin(feat, ((size_t)(b * CINF + c)) * NPT + n0 + tx, f);
    }
    __syncthreads();
    #pragma unroll
    for (int d = 0; d < 4; d++) {
        int n = n0 + ty + d * 8;
        ft[((size_t)(b * NPT + n)) * CINF + c0 + tx] = tile[tx][ty + d * 8];
    }
}

// K0b: pad/convert W_mlp to f32, zero stats
__global__ void k_prep(const void* __restrict__ Wm, float* __restrict__ Wp,
                       float* __restrict__ stats, const int* __restrict__ flag) {
    int f = *flag;
    int e = blockIdx.x * 256 + threadIdx.x;
    if (e < C1 * KP) {
        int o = e / KP, c = e % KP;
        Wp[e] = (c < KDIM) ? ldin(Wm, (size_t)o * KDIM + c, f) : 0.f;
    } else if (e < C1 * KP + 1024) {
        stats[e - C1 * KP] = 0.f;
    }
}

// K1: ball query — first NS hits in ascending j order, fill with first hit.
// contract(off): d2 must round exactly like numpy's (dx*dx + dy*dy) + dz*dz.
__global__ __launch_bounds__(256) void k_knn(const float* __restrict__ ptsf, int* __restrict__ idxb) {
    #pragma clang fp contract(off)
    __shared__ float px[NPT], py[NPT], pz[NPT];
    int b = blockIdx.x >> 3;                       // NPT/256 = 8 chunks per batch
    int i = (blockIdx.x & 7) * 256 + threadIdx.x;
    for (int k = threadIdx.x; k < NPT; k += 256) {
        size_t base = ((size_t)(b * NPT + k)) * 3;
        px[k] = ptsf[base]; py[k] = ptsf[base + 1]; pz[k] = ptsf[base + 2];
    }
    __syncthreads();
    const float R2 = (float)(0.3 * 0.3);           // f32(0.09)
    float qx = px[i], qy = py[i], qz = pz[i];
    int cnt = 0, j0 = 0;
    size_t ob = ((size_t)(b * NPT + i)) * NS;
    for (int j = 0; j < NPT; j++) {
        float dx = qx - px[j];
        float dy = qy - py[j];
        float dz = qz - pz[j];
        float d2 = dx * dx + dy * dy + dz * dz;
        if (d2 < R2) {
            if (cnt == 0) j0 = j;
            if (cnt < NS) idxb[ob + cnt] = j;
            cnt++;
        }
    }
    for (int k = cnt; k < NS; k++) idxb[ob + k] = j0;
}

// K2: per-(b,n) MLP: gather nf (16x272) to LDS (17.4 KB), 256 dots x 16 samples,
// keep per-channel max/min over s + global BN stats.
__global__ __launch_bounds__(128) void k_mlp(const float* __restrict__ ft, const float* __restrict__ Wp,
                                             const int* __restrict__ idxb, const float* __restrict__ ptsf,
                                             float* __restrict__ Hmax, float* __restrict__ Hmin,
                                             float* __restrict__ stats) {
    __shared__ float nf[NS][KP];
    int bid = blockIdx.x;
    int b = bid >> 11, n = bid & (NPT - 1);
    int tid = threadIdx.x;
    float* nfl = &nf[0][0];
    for (int k = tid; k < NS * KP; k += 128) nfl[k] = 0.f;
    __syncthreads();
    size_t pb = ((size_t)(b * NPT + n)) * 3;
    float cx = ptsf[pb], cy = ptsf[pb + 1], cz = ptsf[pb + 2];
    for (int s = 0; s < NS; s++) {
        int j = idxb[((size_t)(b * NPT + n)) * NS + s];
        size_t fb = ((size_t)(b * NPT + j)) * CINF;
        nf[s][3 + tid] = ft[fb + tid];
        nf[s][3 + 128 + tid] = ft[fb + 128 + tid];
        if (tid == 0) {
            #pragma clang fp contract(off)
            size_t qb = ((size_t)(b * NPT + j)) * 3;
            nf[s][0] = (ptsf[qb]     - cx) / 0.3f;
            nf[s][1] = (ptsf[qb + 1] - cy) / 0.3f;
            nf[s][2] = (ptsf[qb + 2] - cz) / 0.3f;
        }
    }
    __syncthreads();
    float acc0[NS], acc1[NS];
    #pragma unroll
    for (int s = 0; s < NS; s++) { acc0[s] = 0.f; acc1[s] = 0.f; }
    const float4* w0p = (const float4*)(Wp + (size_t)tid * KP);
    const float4* w1p = (const float4*)(Wp + (size_t)(tid + 128) * KP);
    for (int c = 0; c < KP / 4; c++) {
        float4 w0 = w0p[c], w1 = w1p[c];
        #pragma unroll
        for (int s = 0; s < NS; s++) {
            float4 v = *(const float4*)&nf[s][c * 4];
            acc0[s] += w0.x * v.x + w0.y * v.y + w0.z * v.z + w0.w * v.w;
            acc1[s] += w1.x * v.x + w1.y * v.y + w1.z * v.z + w1.w * v.w;
        }
    }
    float mx0 = acc0[0], mn0 = acc0[0], s0 = 0.f, q0 = 0.f;
    float mx1 = acc1[0], mn1 = acc1[0], s1 = 0.f, q1 = 0.f;
    #pragma unroll
    for (int s = 0; s < NS; s++) {
        mx0 = fmaxf(mx0, acc0[s]); mn0 = fminf(mn0, acc0[s]); s0 += acc0[s]; q0 += acc0[s] * acc0[s];
        mx1 = fmaxf(mx1, acc1[s]); mn1 = fminf(mn1, acc1[s]); s1 += acc1[s]; q1 += acc1[s] * acc1[s];
    }
    size_t hb = ((size_t)(b * NPT + n)) * C1;
    Hmax[hb + tid] = mx0;       Hmin[hb + tid] = mn0;
    Hmax[hb + 128 + tid] = mx1; Hmin[hb + 128 + tid] = mn1;
    atomicAdd(&stats[tid], s0);       atomicAdd(&stats[256 + tid], q0);
    atomicAdd(&stats[128 + tid], s1); atomicAdd(&stats[256 + 128 + tid], q1);
}

// K4: feats0 = max_s relu(BN(h)) via affine-monotone identity
__global__ void k_feats0(const float* __restrict__ Hmax, const float* __restrict__ Hmin,
                         const float* __restrict__ stats, const float* __restrict__ g,
                         const float* __restrict__ bt, float* __restrict__ f0) {
    int e = blockIdx.x * 256 + threadIdx.x;
    if (e >= NB * NPT * C1) return;
    int o = e & (C1 - 1);
    const float inv = 1.f / 65536.f;
    float m = stats[o] * inv;
    float var = fmaxf(stats[256 + o] * inv - m * m, 0.f);
    float a = g[o] / sqrtf(var + EPSF);
    float d = bt[o] - m * a;
    float h = (a > 0.f) ? Hmax[e] : Hmin[e];
    f0[e] = fmaxf(a * h + d, 0.f);
}

// K5/K7: out[bn][o] = X[bn][:] . W[o][:] + bias[o], accumulate BN stats (W f32 now)
template<int K>
__global__ __launch_bounds__(128) void k_gemm(const float* __restrict__ X, const float* __restrict__ W,
                                              const float* __restrict__ bias, float* __restrict__ out,
                                              float* __restrict__ sum, float* __restrict__ sumsq) {
    __shared__ float xs[32][K];
    int row0 = blockIdx.x * 32;
    int tid = threadIdx.x;
    for (int k = tid; k < 32 * K; k += 128) {
        int r = k / K, c = k % K;
        xs[r][c] = X[(size_t)(row0 + r) * K + c];
    }
    __syncthreads();
    float acc[32];
    #pragma unroll
    for (int j = 0; j < 32; j++) acc[j] = 0.f;
    const float4* wp = (const float4*)(W + (size_t)tid * K);
    for (int c4 = 0; c4 < K / 4; c4++) {
        float4 w = wp[c4];
        #pragma unroll
        for (int j = 0; j < 32; j++) {
            float4 v = *(const float4*)&xs[j][c4 * 4];
            acc[j] += w.x * v.x + w.y * v.y + w.z * v.z + w.w * v.w;
        }
    }
    float bi = bias[tid];
    float s = 0.f, q = 0.f;
    #pragma unroll
    for (int j = 0; j < 32; j++) {
        float h = acc[j] + bi;
        out[(size_t)(row0 + j) * C2 + tid] = h;
        s += h; q += h * h;
    }
    atomicAdd(&sum[tid], s);
    atomicAdd(&sumsq[tid], q);
}

// K6: x = relu(BN(h)) (layer1)
__global__ void k_bnrelu(const float* __restrict__ h, const float* __restrict__ sum,
                         const float* __restrict__ sumsq, const float* __restrict__ g,
                         const float* __restrict__ bt, float* __restrict__ out) {
    int e = blockIdx.x * 256 + threadIdx.x;
    if (e >= NB * NPT * C2) return;
    int o = e & (C2 - 1);
    const float inv = 1.f / 4096.f;
    float m = sum[o] * inv;
    float var = fmaxf(sumsq[o] * inv - m * m, 0.f);
    float a = g[o] / sqrtf(var + EPSF);
    float d = bt[o] - m * a;
    out[e] = fmaxf(a * h[e] + d, 0.f);
}

// K8: feats = relu(BN(h2)); write output 0 (B,C2,N) in the detected dtype + f32 copy for pooling
__global__ void k_final(const float* __restrict__ h2, const float* __restrict__ sum,
                        const float* __restrict__ sumsq, const float* __restrict__ g,
                        const float* __restrict__ bt, float* __restrict__ fp,
                        void* __restrict__ out0, const int* __restrict__ flag) {
    int e = blockIdx.x * 256 + threadIdx.x;
    if (e >= NB * NPT * C2) return;
    int f = *flag;
    int o = e & (C2 - 1);
    int bn = e >> 7;
    int b = bn >> 11, n = bn & (NPT - 1);
    const float inv = 1.f / 4096.f;
    float m = sum[o] * inv;
    float var = fmaxf(sumsq[o] * inv - m * m, 0.f);
    float a = g[o] / sqrtf(var + EPSF);
    float d = bt[o] - m * a;
    float v = fmaxf(a * h2[e] + d, 0.f);
    fp[e] = v;
    size_t oi = ((size_t)(b * C2 + o)) * NPT + n;
    if (f) ((float*)out0)[oi] = v;
    else   ((unsigned short*)out0)[oi] = f2bf(v);
}

// K9: RoI voxel max-pool. One 64-thr block per (b,r); two channel halves; 40 KB LDS.
// feats >= 0 so init-0 == ref's neginf->0. contract(off): numpy-exact boundaries.
__global__ __launch_bounds__(64) void k_pool(const float* __restrict__ ptsf, const float* __restrict__ roisf,
                                             const float* __restrict__ fp, void* __restrict__ d_out,
                                             const int* __restrict__ flag) {
    #pragma clang fp contract(off)
    __shared__ float pooled[NVOX * 64];
    __shared__ int list[NPT];
    __shared__ int cnt;
    int f = *flag;
    int bid = blockIdx.x;
    int b = bid >> 7;
    int tid = threadIdx.x;
    if (tid == 0) cnt = 0;
    size_t rb = ((size_t)bid) * 7;
    float cx = roisf[rb], cy = roisf[rb + 1], cz = roisf[rb + 2];
    float hx = roisf[rb + 3] * 0.5f;
    float hy = roisf[rb + 4] * 0.5f;
    float hz = roisf[rb + 5] * 0.5f;
    float ry = roisf[rb + 6];
    float cf = (float)cos((double)ry);
    float sf = (float)sin((double)ry);
    __syncthreads();
    for (int n = tid; n < NPT; n += 64) {
        size_t pb = ((size_t)(b * NPT + n)) * 3;
        float rx  = ptsf[pb]     - cx;
        float ryy = ptsf[pb + 1] - cy;
        float rz  = ptsf[pb + 2] - cz;
        float lx = rx * cf + ryy * sf;
        float ly = -rx * sf + ryy * cf;
        if (fabsf(lx) < hx && fabsf(ly) < hy && fabsf(rz) < hz) {
            int vx = (int)fminf(fmaxf(floorf((lx + hx) / (2.f * hx) * 5.f), 0.f), 4.f);
            int vy = (int)fminf(fmaxf(floorf((ly + hy) / (2.f * hy) * 5.f), 0.f), 4.f);
            int vz = (int)fminf(fmaxf(floorf((rz + hz) / (2.f * hz) * 5.f), 0.f), 4.f);
            int vox = (vx * 5 + vy) * 5 + vz;
            int pos = atomicAdd(&cnt, 1);
            list[pos] = (vox << 16) | n;
        }
    }
    __syncthreads();
    int m = cnt;
    size_t ob = (size_t)524288 + (size_t)bid * (NVOX * C2);   // element offset of output 1
    for (int half = 0; half < 2; half++) {
        for (int k = tid; k < NVOX * 64; k += 64) pooled[k] = 0.f;
        __syncthreads();
        int c = half * 64 + tid;
        for (int e = 0; e < m; e++) {
            int u = list[e];
            int n = u & 0xFFFF, vox = u >> 16;
            float v = fp[((size_t)(b * NPT + n)) * C2 + c];
            float* p = &pooled[vox * 64 + tid];
            *p = fmaxf(*p, v);
        }
        __syncthreads();
        for (int k = tid; k < NVOX * 64; k += 64) {
            int vox = k >> 6, cc = k & 63;
            size_t oi = ob + (size_t)vox * C2 + half * 64 + cc;
            float v = pooled[k];
            if (f) ((float*)d_out)[oi] = v;
            else   ((unsigned short*)d_out)[oi] = f2bf(v);
        }
        __syncthreads();
    }
}

extern "C" void kernel_launch(void* const* d_in, const int* in_sizes, int n_in,
                              void* d_out, int out_size, void* d_ws, size_t ws_size,
                              hipStream_t stream) {
    const void* pts  = d_in[0];
    const void* feat = d_in[1];
    const void* rois = d_in[2];
    const void* Wm   = d_in[3];
    const void* gm   = d_in[4];
    const void* btm  = d_in[5];
    const void* W1   = d_in[6];
    const void* b1   = d_in[7];
    const void* g1   = d_in[8];
    const void* bt1  = d_in[9];
    const void* W2   = d_in[10];
    const void* b2   = d_in[11];
    const void* g2   = d_in[12];
    const void* bt2  = d_in[13];

    float* ws     = (float*)d_ws;
    int*   flag   = (int*)ws;                  // @0
    float* ptsf   = ws + 16;                   // 12288
    float* roisf  = ws + 12304;                // 1792
    float* params = ws + 14096;                // 50432
    float* Wp     = ws + 64528;                // 69632
    float* stats  = ws + 134160;               // 1024
    int*   idxb   = (int*)(ws + 135184);       // 65536
    float* ft     = ws + 200720;               // 1048576 (reused as f0)
    float* Hmax   = ws + 1249296;              // 1048576 (reused as h1|x1)
    float* Hmin   = ws + 2297872;              // 1048576 (reused as h2|fp)
    float* f0 = ft;
    float* h1 = Hmax;
    float* x1 = Hmax + 524288;
    float* h2 = Hmin;
    float* fp = Hmin + 524288;

    k_detect<<<1, 256, 0, stream>>>(Wm, flag);
    k_cvt<<<dim3(128, 12), 256, 0, stream>>>(pts, rois, gm, btm, W1, b1, g1, bt1,
                                             W2, b2, g2, bt2, ptsf, roisf, params, flag);
    k_transpose<<<dim3(NPT / 32, CINF / 32, NB), dim3(32, 8), 0, stream>>>(feat, ft, flag);
    k_prep<<<276, 256, 0, stream>>>(Wm, Wp, stats, flag);
    k_knn<<<NB * (NPT / 256), 256, 0, stream>>>(ptsf, idxb);
    k_mlp<<<NB * NPT, 128, 0, stream>>>(ft, Wp, idxb, ptsf, Hmax, Hmin, stats);
    k_feats0<<<(NB * NPT * C1) / 256, 256, 0, stream>>>(Hmax, Hmin, stats, params + 0, params + 256, f0);
    k_gemm<256><<<(NB * NPT) / 32, 128, 0, stream>>>(f0, params + 512, params + 33280, h1, stats + 512, stats + 640);
    k_bnrelu<<<(NB * NPT * C2) / 256, 256, 0, stream>>>(h1, stats + 512, stats + 640, params + 33408, params + 33536, x1);
    k_gemm<128><<<(NB * NPT) / 32, 128, 0, stream>>>(x1, params + 33664, params + 50048, h2, stats + 768, stats + 896);
    k_final<<<(NB * NPT * C2) / 256, 256, 0, stream>>>(h2, stats + 768, stats + 896, params + 50176, params + 50304, fp, d_out, flag);
    k_pool<<<NB * NROI, 64, 0, stream>>>(ptsf, roisf, fp, d_out, flag);
}

// Round 5
// 604.961 us; speedup vs baseline: 1.8837x; 1.8837x over previous
//
#include <hip/hip_runtime.h>
#include <hip/hip_bf16.h>

typedef __hip_bfloat16 bf16;
typedef unsigned short u16;

#define NB   2
#define NPT  2048
#define NROI 128
#define CINF 256
#define NS   16
#define KDIM 259     // CIN + 3
#define KP2  288     // K padded to multiple of 32 for MFMA (cols: 0..255 feat, 256..258 gx, rest 0)
#define C1   256     // mlp out channels
#define C2   128     // layer1/2 out channels
#define NVOX 125
#define EPSF 1e-5f

typedef __bf16 bf16x8 __attribute__((ext_vector_type(8)));
typedef float  f32x4  __attribute__((ext_vector_type(4)));

// flag-branched input load: inputs are either all-bf16 or all-f32 (runtime-detected)
__device__ __forceinline__ float ldin(const void* p, size_t i, int f32flag) {
    if (f32flag) return ((const float*)p)[i];
    unsigned short u = ((const unsigned short*)p)[i];
    return __uint_as_float(((unsigned)u) << 16);
}

// round-to-nearest-even f32 -> bf16 (matches numpy)
__device__ __forceinline__ unsigned short f2bf(float x) {
    unsigned u = __float_as_uint(x);
    u += 0x7FFFu + ((u >> 16) & 1u);
    return (unsigned short)(u >> 16);
}

// ---------------- ws layout (float units), total 3,313,680 f = 13.25 MB ----------------
// flag  @0        [16]
// ptsf  @16       [12288]
// roisf @12304    [1792]
// params@14096    [50432]  [gm 0|btm 256|W1 512|b1 33280|g1 33408|bt1 33536|W2 33664|b2 50048|g2 50176|bt2 50304]
// Wbf   @64528    [36864]  (256x288 bf16, repacked: col k<256 -> W[:,3+k], 256..258 -> W[:,0..2], pad 0)
// stats @101392   [1024]   [sum0 0|sq0 256|sum1 512|sq1 640|sum2 768|sq2 896]
// idxb  @102416   [65536 ints]
// ftbf  @167952   [524288] (2x2048x256 bf16)   -- f0 overlays @167952 [1048576]
// Hmax  @1216528  [1048576]                     -- h1 @1216528, x1 @1740816 overlay after feats0
// Hmin  @2265104  [1048576]                     -- h2 @2265104, fp @2789392 overlay after feats0

// D0: detect input dtype (true-bf16 W_mlp has |w|<=~0.2; f32-misread-as-bf16 -> huge/NaN)
__global__ void k_detect(const void* __restrict__ Wm, int* __restrict__ flag) {
    __shared__ int f;
    int tid = threadIdx.x;
    if (tid == 0) f = 0;
    __syncthreads();
    #pragma unroll
    for (int r = 0; r < 4; r++) {
        unsigned short u = ((const unsigned short*)Wm)[r * 256 + tid];
        float v = __uint_as_float(((unsigned)u) << 16);
        if (!(fabsf(v) <= 1e4f)) atomicOr(&f, 1);
    }
    __syncthreads();
    if (tid == 0) *flag = f;
}

// D1: convert pts/rois/params to f32 scratch
__global__ void k_cvt(const void* __restrict__ pts, const void* __restrict__ rois,
                      const void* __restrict__ gm, const void* __restrict__ btm,
                      const void* __restrict__ W1, const void* __restrict__ b1,
                      const void* __restrict__ g1, const void* __restrict__ bt1,
                      const void* __restrict__ W2, const void* __restrict__ b2,
                      const void* __restrict__ g2, const void* __restrict__ bt2,
                      float* __restrict__ ptsf, float* __restrict__ roisf,
                      float* __restrict__ params, const int* __restrict__ flag) {
    int f = *flag;
    int e = blockIdx.x * 256 + threadIdx.x;
    const void* src; float* dst; int n;
    switch (blockIdx.y) {
        case 0:  src = pts; dst = ptsf;           n = NB * NPT * 3; break;
        case 1:  src = rois; dst = roisf;         n = NB * NROI * 7; break;
        case 2:  src = gm;  dst = params + 0;     n = 256; break;
        case 3:  src = btm; dst = params + 256;   n = 256; break;
        case 4:  src = W1;  dst = params + 512;   n = 32768; break;
        case 5:  src = b1;  dst = params + 33280; n = 128; break;
        case 6:  src = g1;  dst = params + 33408; n = 128; break;
        case 7:  src = bt1; dst = params + 33536; n = 128; break;
        case 8:  src = W2;  dst = params + 33664; n = 16384; break;
        case 9:  src = b2;  dst = params + 50048; n = 128; break;
        case 10: src = g2;  dst = params + 50176; n = 128; break;
        default: src = bt2; dst = params + 50304; n = 128; break;
    }
    if (e < n) dst[e] = ldin(src, e, f);
}

// K0a: transpose features (B,CIN,N) -> ftbf (B,N,CIN) bf16
__global__ void k_transpose(const void* __restrict__ feat, u16* __restrict__ ftbf,
                            const int* __restrict__ flag) {
    __shared__ float tile[32][33];
    int f = *flag;
    int b = blockIdx.z;
    int n0 = blockIdx.x * 32, c0 = blockIdx.y * 32;
    int tx = threadIdx.x, ty = threadIdx.y;  // 32x8
    #pragma unroll
    for (int d = 0; d < 4; d++) {
        int c = c0 + ty + d * 8;
        tile[ty + d * 8][tx] = ldin(feat, ((size_t)(b * CINF + c)) * NPT + n0 + tx, f);
    }
    __syncthreads();
    #pragma unroll
    for (int d = 0; d < 4; d++) {
        int n = n0 + ty + d * 8;
        ftbf[((size_t)(b * NPT + n)) * CINF + c0 + tx] = f2bf(tile[tx][ty + d * 8]);
    }
}

// K0b: repack W_mlp -> Wbf [256][288] bf16 (feat cols first, coords at 256..258), zero stats
__global__ void k_prep(const void* __restrict__ Wm, u16* __restrict__ wbf,
                       float* __restrict__ stats, const int* __restrict__ flag) {
    int f = *flag;
    int e = blockIdx.x * 256 + threadIdx.x;
    if (e < 256 * KP2) {
        int o = e / KP2, k = e % KP2;
        float v = 0.f;
        if (k < 256)      v = ldin(Wm, (size_t)o * KDIM + 3 + k, f);
        else if (k < 259) v = ldin(Wm, (size_t)o * KDIM + (k - 256), f);
        wbf[e] = f2bf(v);
    } else if (e < 256 * KP2 + 1024) {
        stats[e - 256 * KP2] = 0.f;
    }
}

// K1: ball query — first NS hits in ascending j order, fill with first hit.
__global__ __launch_bounds__(64) void k_knn(const float* __restrict__ ptsf, int* __restrict__ idxb) {
    #pragma clang fp contract(off)
    __shared__ float px[NPT], py[NPT], pz[NPT];
    int b = blockIdx.x >> 5;                       // 32 blocks of 64 queries per batch
    int i = (blockIdx.x & 31) * 64 + threadIdx.x;
    for (int k = threadIdx.x; k < NPT; k += 64) {
        size_t base = ((size_t)(b * NPT + k)) * 3;
        px[k] = ptsf[base]; py[k] = ptsf[base + 1]; pz[k] = ptsf[base + 2];
    }
    __syncthreads();
    const float R2 = (float)(0.3 * 0.3);
    float qx = px[i], qy = py[i], qz = pz[i];
    int cnt = 0, j0 = 0;
    size_t ob = ((size_t)(b * NPT + i)) * NS;
    for (int j = 0; j < NPT; j++) {
        float dx = qx - px[j];
        float dy = qy - py[j];
        float dz = qz - pz[j];
        float d2 = dx * dx + dy * dy + dz * dz;
        if (d2 < R2) {
            if (cnt == 0) j0 = j;
            if (cnt < NS) idxb[ob + cnt] = j;
            cnt++;
        }
        if (__all(cnt >= NS)) break;
    }
    for (int k = cnt; k < NS; k++) idxb[ob + k] = j0;
}

// K2 (MFMA): H = NF(65536x288) . Wbf^T(288x256), fused s=16 max/min/sum/sumsq epilogue.
// Grid: 1024 blocks x 256 thr = 4096 waves. Wave = 64 rows (4 points) x 64 cols, 4x4 16x16 tiles.
// A-frags gathered straight from ftbf (L2-resident) via idxb; B-frags from Wbf (L2-resident).
// Frag maps: A row=lane&15,k=(lane>>4)*8+j ; B col=lane&15,same k ; D col=lane&15,row=(lane>>4)*4+reg.
__global__ __launch_bounds__(256) void k_mlp_mfma(const u16* __restrict__ ftbf, const u16* __restrict__ wbf,
                                                  const int* __restrict__ idxb, const float* __restrict__ ptsf,
                                                  float* __restrict__ Hmax, float* __restrict__ Hmin,
                                                  float* __restrict__ stats) {
    int bid = blockIdx.x;
    int nb = bid & 3, mb = bid >> 2;               // 4 consecutive blocks share A rows (L2 locality)
    int n0 = nb * 64;
    int w = threadIdx.x >> 6, lane = threadIdx.x & 63;
    int rbase = mb * 256 + w * 64;                 // wave's global row base (row = (b*N+n)*16+s)
    int b = rbase >> 15;
    int lg = lane >> 4, lr = lane & 15;

    size_t boff[4];
    #pragma unroll
    for (int ct = 0; ct < 4; ct++)
        boff[ct] = (size_t)(n0 + ct * 16 + lr) * KP2 + lg * 8;

    size_t aoff[4];
    uint4 lastA[4];
    #pragma unroll
    for (int rt = 0; rt < 4; rt++) {
        int row = rbase + rt * 16 + lr;
        int j = idxb[row];
        aoff[rt] = ((size_t)(b * NPT + j)) * CINF + (size_t)lg * 8;
        int pt = (rbase + rt * 16) >> 4;
        int n = pt & (NPT - 1);
        size_t cb = ((size_t)(b * NPT + n)) * 3;
        size_t jb = ((size_t)(b * NPT + j)) * 3;
        unsigned g0 = f2bf((ptsf[jb]     - ptsf[cb])     / 0.3f);
        unsigned g1 = f2bf((ptsf[jb + 1] - ptsf[cb + 1]) / 0.3f);
        unsigned g2 = f2bf((ptsf[jb + 2] - ptsf[cb + 2]) / 0.3f);
        uint4 la; la.x = 0u; la.y = 0u; la.z = 0u; la.w = 0u;
        if (lg == 0) { la.x = g0 | (g1 << 16); la.y = g2; }
        lastA[rt] = la;
    }

    f32x4 acc[4][4];
    #pragma unroll
    for (int rt = 0; rt < 4; rt++)
        #pragma unroll
        for (int ct = 0; ct < 4; ct++)
            acc[rt][ct] = (f32x4){0.f, 0.f, 0.f, 0.f};

    #pragma unroll
    for (int k0 = 0; k0 < 256; k0 += 32) {
        bf16x8 af[4], bfr[4];
        #pragma unroll
        for (int rt = 0; rt < 4; rt++)
            af[rt] = __builtin_bit_cast(bf16x8, *(const uint4*)(ftbf + aoff[rt] + k0));
        #pragma unroll
        for (int ct = 0; ct < 4; ct++)
            bfr[ct] = __builtin_bit_cast(bf16x8, *(const uint4*)(wbf + boff[ct] + k0));
        #pragma unroll
        for (int rt = 0; rt < 4; rt++)
            #pragma unroll
            for (int ct = 0; ct < 4; ct++)
                acc[rt][ct] = __builtin_amdgcn_mfma_f32_16x16x32_bf16(af[rt], bfr[ct], acc[rt][ct], 0, 0, 0);
    }
    {   // last K-step: cols 256..287 (coords in A regs; Wbf has matching cols + zero pad)
        bf16x8 bfr[4];
        #pragma unroll
        for (int ct = 0; ct < 4; ct++)
            bfr[ct] = __builtin_bit_cast(bf16x8, *(const uint4*)(wbf + boff[ct] + 256));
        #pragma unroll
        for (int rt = 0; rt < 4; rt++) {
            bf16x8 af = __builtin_bit_cast(bf16x8, lastA[rt]);
            #pragma unroll
            for (int ct = 0; ct < 4; ct++)
                acc[rt][ct] = __builtin_amdgcn_mfma_f32_16x16x32_bf16(af, bfr[ct], acc[rt][ct], 0, 0, 0);
        }
    }

    // epilogue: reduce the 16 s-rows of each (point, 16-col tile)
    float ssum[4] = {0.f, 0.f, 0.f, 0.f}, ssq[4] = {0.f, 0.f, 0.f, 0.f};
    #pragma unroll
    for (int rt = 0; rt < 4; rt++) {
        int pt = (rbase >> 4) + rt;
        #pragma unroll
        for (int ct = 0; ct < 4; ct++) {
            f32x4 a = acc[rt][ct];
            float mx = fmaxf(fmaxf(a.x, a.y), fmaxf(a.z, a.w));
            float mn = fminf(fminf(a.x, a.y), fminf(a.z, a.w));
            float sm = (a.x + a.y) + (a.z + a.w);
            float sq = (a.x * a.x + a.y * a.y) + (a.z * a.z + a.w * a.w);
            mx = fmaxf(mx, __shfl_xor(mx, 16)); mx = fmaxf(mx, __shfl_xor(mx, 32));
            mn = fminf(mn, __shfl_xor(mn, 16)); mn = fminf(mn, __shfl_xor(mn, 32));
            sm += __shfl_xor(sm, 16); sm += __shfl_xor(sm, 32);
            sq += __shfl_xor(sq, 16); sq += __shfl_xor(sq, 32);
            if (lane < 16) {
                int c = n0 + ct * 16 + lr;
                Hmax[(size_t)pt * C1 + c] = mx;
                Hmin[(size_t)pt * C1 + c] = mn;
            }
            ssum[ct] += sm; ssq[ct] += sq;
        }
    }
    #pragma unroll
    for (int ct = 0; ct < 4; ct++) {
        if (lane < 16) {
            int c = n0 + ct * 16 + lr;
            atomicAdd(&stats[c], ssum[ct]);
            atomicAdd(&stats[256 + c], ssq[ct]);
        }
    }
}

// K4: feats0 = max_s relu(BN(h)) via affine-monotone identity
__global__ void k_feats0(const float* __restrict__ Hmax, const float* __restrict__ Hmin,
                         const float* __restrict__ stats, const float* __restrict__ g,
                         const float* __restrict__ bt, float* __restrict__ f0) {
    int e = blockIdx.x * 256 + threadIdx.x;
    if (e >= NB * NPT * C1) return;
    int o = e & (C1 - 1);
    const float inv = 1.f / 65536.f;
    float m = stats[o] * inv;
    float var = fmaxf(stats[256 + o] * inv - m * m, 0.f);
    float a = g[o] / sqrtf(var + EPSF);
    float d = bt[o] - m * a;
    float h = (a > 0.f) ? Hmax[e] : Hmin[e];
    f0[e] = fmaxf(a * h + d, 0.f);
}

// K5/K7: out[bn][o] = X[bn][:] . W[o][:] + bias[o], accumulate BN stats
template<int K>
__global__ __launch_bounds__(128) void k_gemm(const float* __restrict__ X, const float* __restrict__ W,
                                              const float* __restrict__ bias, float* __restrict__ out,
                                              float* __restrict__ sum, float* __restrict__ sumsq) {
    __shared__ float xs[32][K];
    int row0 = blockIdx.x * 32;
    int tid = threadIdx.x;
    for (int k = tid; k < 32 * K; k += 128) {
        int r = k / K, c = k % K;
        xs[r][c] = X[(size_t)(row0 + r) * K + c];
    }
    __syncthreads();
    float acc[32];
    #pragma unroll
    for (int j = 0; j < 32; j++) acc[j] = 0.f;
    const float4* wp = (const float4*)(W + (size_t)tid * K);
    for (int c4 = 0; c4 < K / 4; c4++) {
        float4 w = wp[c4];
        #pragma unroll
        for (int j = 0; j < 32; j++) {
            float4 v = *(const float4*)&xs[j][c4 * 4];
            acc[j] += w.x * v.x + w.y * v.y + w.z * v.z + w.w * v.w;
        }
    }
    float bi = bias[tid];
    float s = 0.f, q = 0.f;
    #pragma unroll
    for (int j = 0; j < 32; j++) {
        float h = acc[j] + bi;
        out[(size_t)(row0 + j) * C2 + tid] = h;
        s += h; q += h * h;
    }
    atomicAdd(&sum[tid], s);
    atomicAdd(&sumsq[tid], q);
}

// K6: x = relu(BN(h)) (layer1)
__global__ void k_bnrelu(const float* __restrict__ h, const float* __restrict__ sum,
                         const float* __restrict__ sumsq, const float* __restrict__ g,
                         const float* __restrict__ bt, float* __restrict__ out) {
    int e = blockIdx.x * 256 + threadIdx.x;
    if (e >= NB * NPT * C2) return;
    int o = e & (C2 - 1);
    const float inv = 1.f / 4096.f;
    float m = sum[o] * inv;
    float var = fmaxf(sumsq[o] * inv - m * m, 0.f);
    float a = g[o] / sqrtf(var + EPSF);
    float d = bt[o] - m * a;
    out[e] = fmaxf(a * h[e] + d, 0.f);
}

// K8: feats = relu(BN(h2)); write output 0 (B,C2,N) in detected dtype + f32 copy for pooling
__global__ void k_final(const float* __restrict__ h2, const float* __restrict__ sum,
                        const float* __restrict__ sumsq, const float* __restrict__ g,
                        const float* __restrict__ bt, float* __restrict__ fp,
                        void* __restrict__ out0, const int* __restrict__ flag) {
    int e = blockIdx.x * 256 + threadIdx.x;
    if (e >= NB * NPT * C2) return;
    int f = *flag;
    int o = e & (C2 - 1);
    int bn = e >> 7;
    int b = bn >> 11, n = bn & (NPT - 1);
    const float inv = 1.f / 4096.f;
    float m = sum[o] * inv;
    float var = fmaxf(sumsq[o] * inv - m * m, 0.f);
    float a = g[o] / sqrtf(var + EPSF);
    float d = bt[o] - m * a;
    float v = fmaxf(a * h2[e] + d, 0.f);
    fp[e] = v;
    size_t oi = ((size_t)(b * C2 + o)) * NPT + n;
    if (f) ((float*)out0)[oi] = v;
    else   ((unsigned short*)out0)[oi] = f2bf(v);
}

// K9: RoI voxel max-pool. One 64-thr block per (b,r); two channel halves; 40 KB LDS.
__global__ __launch_bounds__(64) void k_pool(const float* __restrict__ ptsf, const float* __restrict__ roisf,
                                             const float* __restrict__ fp, void* __restrict__ d_out,
                                             const int* __restrict__ flag) {
    #pragma clang fp contract(off)
    __shared__ float pooled[NVOX * 64];
    __shared__ int list[NPT];
    __shared__ int cnt;
    int f = *flag;
    int bid = blockIdx.x;
    int b = bid >> 7;
    int tid = threadIdx.x;
    if (tid == 0) cnt = 0;
    size_t rb = ((size_t)bid) * 7;
    float cx = roisf[rb], cy = roisf[rb + 1], cz = roisf[rb + 2];
    float hx = roisf[rb + 3] * 0.5f;
    float hy = roisf[rb + 4] * 0.5f;
    float hz = roisf[rb + 5] * 0.5f;
    float ry = roisf[rb + 6];
    float cf = (float)cos((double)ry);
    float sf = (float)sin((double)ry);
    __syncthreads();
    for (int n = tid; n < NPT; n += 64) {
        size_t pb = ((size_t)(b * NPT + n)) * 3;
        float rx  = ptsf[pb]     - cx;
        float ryy = ptsf[pb + 1] - cy;
        float rz  = ptsf[pb + 2] - cz;
        float lx = rx * cf + ryy * sf;
        float ly = -rx * sf + ryy * cf;
        if (fabsf(lx) < hx && fabsf(ly) < hy && fabsf(rz) < hz) {
            int vx = (int)fminf(fmaxf(floorf((lx + hx) / (2.f * hx) * 5.f), 0.f), 4.f);
            int vy = (int)fminf(fmaxf(floorf((ly + hy) / (2.f * hy) * 5.f), 0.f), 4.f);
            int vz = (int)fminf(fmaxf(floorf((rz + hz) / (2.f * hz) * 5.f), 0.f), 4.f);
            int vox = (vx * 5 + vy) * 5 + vz;
            int pos = atomicAdd(&cnt, 1);
            list[pos] = (vox << 16) | n;
        }
    }
    __syncthreads();
    int m = cnt;
    size_t ob = (size_t)524288 + (size_t)bid * (NVOX * C2);
    for (int half = 0; half < 2; half++) {
        for (int k = tid; k < NVOX * 64; k += 64) pooled[k] = 0.f;
        __syncthreads();
        int c = half * 64 + tid;
        for (int e = 0; e < m; e++) {
            int u = list[e];
            int n = u & 0xFFFF, vox = u >> 16;
            float v = fp[((size_t)(b * NPT + n)) * C2 + c];
            float* p = &pooled[vox * 64 + tid];
            *p = fmaxf(*p, v);
        }
        __syncthreads();
        for (int k = tid; k < NVOX * 64; k += 64) {
            int vox = k >> 6, cc = k & 63;
            size_t oi = ob + (size_t)vox * C2 + half * 64 + cc;
            float v = pooled[k];
            if (f) ((float*)d_out)[oi] = v;
            else   ((unsigned short*)d_out)[oi] = f2bf(v);
        }
        __syncthreads();
    }
}

extern "C" void kernel_launch(void* const* d_in, const int* in_sizes, int n_in,
                              void* d_out, int out_size, void* d_ws, size_t ws_size,
                              hipStream_t stream) {
    const void* pts  = d_in[0];
    const void* feat = d_in[1];
    const void* rois = d_in[2];
    const void* Wm   = d_in[3];
    const void* gm   = d_in[4];
    const void* btm  = d_in[5];
    const void* W1   = d_in[6];
    const void* b1   = d_in[7];
    const void* g1   = d_in[8];
    const void* bt1  = d_in[9];
    const void* W2   = d_in[10];
    const void* b2   = d_in[11];
    const void* g2   = d_in[12];
    const void* bt2  = d_in[13];

    float* ws     = (float*)d_ws;
    int*   flag   = (int*)ws;                  // @0
    float* ptsf   = ws + 16;
    float* roisf  = ws + 12304;
    float* params = ws + 14096;
    u16*   wbf    = (u16*)(ws + 64528);        // 256x288 bf16
    float* stats  = ws + 101392;
    int*   idxb   = (int*)(ws + 102416);
    u16*   ftbf   = (u16*)(ws + 167952);       // 2x2048x256 bf16
    float* Hmax   = ws + 1216528;
    float* Hmin   = ws + 2265104;
    float* f0     = ws + 167952;               // overlays ftbf (dead after MFMA)
    float* h1     = ws + 1216528;              // overlays Hmax (dead after feats0)
    float* x1     = ws + 1740816;
    float* h2     = ws + 2265104;              // overlays Hmin
    float* fp     = ws + 2789392;

    k_detect<<<1, 256, 0, stream>>>(Wm, flag);
    k_cvt<<<dim3(128, 12), 256, 0, stream>>>(pts, rois, gm, btm, W1, b1, g1, bt1,
                                             W2, b2, g2, bt2, ptsf, roisf, params, flag);
    k_transpose<<<dim3(NPT / 32, CINF / 32, NB), dim3(32, 8), 0, stream>>>(feat, ftbf, flag);
    k_prep<<<292, 256, 0, stream>>>(Wm, wbf, stats, flag);
    k_knn<<<NB * 32, 64, 0, stream>>>(ptsf, idxb);
    k_mlp_mfma<<<1024, 256, 0, stream>>>(ftbf, wbf, idxb, ptsf, Hmax, Hmin, stats);
    k_feats0<<<(NB * NPT * C1) / 256, 256, 0, stream>>>(Hmax, Hmin, stats, params + 0, params + 256, f0);
    k_gemm<256><<<(NB * NPT) / 32, 128, 0, stream>>>(f0, params + 512, params + 33280, h1, stats + 512, stats + 640);
    k_bnrelu<<<(NB * NPT * C2) / 256, 256, 0, stream>>>(h1, stats + 512, stats + 640, params + 33408, params + 33536, x1);
    k_gemm<128><<<(NB * NPT) / 32, 128, 0, stream>>>(x1, params + 33664, params + 50048, h2, stats + 768, stats + 896);
    k_final<<<(NB * NPT * C2) / 256, 256, 0, stream>>>(h2, stats + 768, stats + 896, params + 50176, params + 50304, fp, d_out, flag);
    k_pool<<<NB * NROI, 64, 0, stream>>>(ptsf, roisf, fp, d_out, flag);
}

// Round 6
// 322.475 us; speedup vs baseline: 3.5338x; 1.8760x over previous
//
#include <hip/hip_runtime.h>
#include <hip/hip_bf16.h>

typedef __hip_bfloat16 bf16;
typedef unsigned short u16;

#define NB   2
#define NPT  2048
#define NROI 128
#define CINF 256
#define NS   16
#define KDIM 259     // CIN + 3
#define KP2  288     // K padded to multiple of 32 for MFMA (cols: 0..255 feat, 256..258 gx, rest 0)
#define C1   256     // mlp out channels
#define C2   128     // layer1/2 out channels
#define NVOX 125
#define EPSF 1e-5f

typedef __bf16 bf16x8 __attribute__((ext_vector_type(8)));
typedef float  f32x4  __attribute__((ext_vector_type(4)));

// flag-branched input load: inputs are either all-bf16 or all-f32 (runtime-detected)
__device__ __forceinline__ float ldin(const void* p, size_t i, int f32flag) {
    if (f32flag) return ((const float*)p)[i];
    unsigned short u = ((const unsigned short*)p)[i];
    return __uint_as_float(((unsigned)u) << 16);
}

// round-to-nearest-even f32 -> bf16 (matches numpy)
__device__ __forceinline__ unsigned short f2bf(float x) {
    unsigned u = __float_as_uint(x);
    u += 0x7FFFu + ((u >> 16) & 1u);
    return (unsigned short)(u >> 16);
}

// ---------------- ws layout (float units), total 3,325,968 f = 13.30 MB ----------------
// flag  @0        [16]
// ptsf  @16       [12288]
// roisf @12304    [1792]
// params@14096    [50432]
// Wbf   @64528    [36864]  (256x288 bf16)
// stats @101392   [1024]
// idxb  @102416   [65536 ints]
// ftbf  @167952   [524288] (bf16 2x2048x256)  -- f0 overlays [1048576]
// Hmax  @1216528  [1048576]  -- h1 @1216528, x1 @1740816 overlay
// Hmin  @2265104  [1048576]  -- h2 @2265104, fp @2789392 overlay
// psx   @3313680  [4096]; psy @3317776 [4096]; psz @3321872 [4096]

// D0: detect input dtype (true-bf16 W_mlp has |w|<=~0.2; f32-misread-as-bf16 -> huge/NaN)
__global__ void k_detect(const void* __restrict__ Wm, int* __restrict__ flag) {
    __shared__ int f;
    int tid = threadIdx.x;
    if (tid == 0) f = 0;
    __syncthreads();
    #pragma unroll
    for (int r = 0; r < 4; r++) {
        unsigned short u = ((const unsigned short*)Wm)[r * 256 + tid];
        float v = __uint_as_float(((unsigned)u) << 16);
        if (!(fabsf(v) <= 1e4f)) atomicOr(&f, 1);
    }
    __syncthreads();
    if (tid == 0) *flag = f;
}

// D1: convert pts/rois/params to f32 scratch
__global__ void k_cvt(const void* __restrict__ pts, const void* __restrict__ rois,
                      const void* __restrict__ gm, const void* __restrict__ btm,
                      const void* __restrict__ W1, const void* __restrict__ b1,
                      const void* __restrict__ g1, const void* __restrict__ bt1,
                      const void* __restrict__ W2, const void* __restrict__ b2,
                      const void* __restrict__ g2, const void* __restrict__ bt2,
                      float* __restrict__ ptsf, float* __restrict__ roisf,
                      float* __restrict__ params, const int* __restrict__ flag) {
    int f = *flag;
    int e = blockIdx.x * 256 + threadIdx.x;
    const void* src; float* dst; int n;
    switch (blockIdx.y) {
        case 0:  src = pts; dst = ptsf;           n = NB * NPT * 3; break;
        case 1:  src = rois; dst = roisf;         n = NB * NROI * 7; break;
        case 2:  src = gm;  dst = params + 0;     n = 256; break;
        case 3:  src = btm; dst = params + 256;   n = 256; break;
        case 4:  src = W1;  dst = params + 512;   n = 32768; break;
        case 5:  src = b1;  dst = params + 33280; n = 128; break;
        case 6:  src = g1;  dst = params + 33408; n = 128; break;
        case 7:  src = bt1; dst = params + 33536; n = 128; break;
        case 8:  src = W2;  dst = params + 33664; n = 16384; break;
        case 9:  src = b2;  dst = params + 50048; n = 128; break;
        case 10: src = g2;  dst = params + 50176; n = 128; break;
        default: src = bt2; dst = params + 50304; n = 128; break;
    }
    if (e < n) dst[e] = ldin(src, e, f);
}

// D2: split points into SoA for the coalesced ballot-scan knn
__global__ void k_soa(const float* __restrict__ ptsf, float* __restrict__ psx,
                      float* __restrict__ psy, float* __restrict__ psz) {
    int e = blockIdx.x * 256 + threadIdx.x;
    if (e < NB * NPT) {
        psx[e] = ptsf[e * 3 + 0];
        psy[e] = ptsf[e * 3 + 1];
        psz[e] = ptsf[e * 3 + 2];
    }
}

// K0a: transpose features (B,CIN,N) -> ftbf (B,N,CIN) bf16
__global__ void k_transpose(const void* __restrict__ feat, u16* __restrict__ ftbf,
                            const int* __restrict__ flag) {
    __shared__ float tile[32][33];
    int f = *flag;
    int b = blockIdx.z;
    int n0 = blockIdx.x * 32, c0 = blockIdx.y * 32;
    int tx = threadIdx.x, ty = threadIdx.y;  // 32x8
    #pragma unroll
    for (int d = 0; d < 4; d++) {
        int c = c0 + ty + d * 8;
        tile[ty + d * 8][tx] = ldin(feat, ((size_t)(b * CINF + c)) * NPT + n0 + tx, f);
    }
    __syncthreads();
    #pragma unroll
    for (int d = 0; d < 4; d++) {
        int n = n0 + ty + d * 8;
        ftbf[((size_t)(b * NPT + n)) * CINF + c0 + tx] = f2bf(tile[tx][ty + d * 8]);
    }
}

// K0b: repack W_mlp -> Wbf [256][288] bf16, zero stats
__global__ void k_prep(const void* __restrict__ Wm, u16* __restrict__ wbf,
                       float* __restrict__ stats, const int* __restrict__ flag) {
    int f = *flag;
    int e = blockIdx.x * 256 + threadIdx.x;
    if (e < 256 * KP2) {
        int o = e / KP2, k = e % KP2;
        float v = 0.f;
        if (k < 256)      v = ldin(Wm, (size_t)o * KDIM + 3 + k, f);
        else if (k < 259) v = ldin(Wm, (size_t)o * KDIM + (k - 256), f);
        wbf[e] = f2bf(v);
    } else if (e < 256 * KP2 + 1024) {
        stats[e - 256 * KP2] = 0.f;
    }
}

// K1: ball query, wave-per-query ballot scan. First NS hits in ascending j;
// all position writes parallel via popcount-prefix; uniform early exit.
__global__ __launch_bounds__(256) void k_knn2(const float* __restrict__ psx, const float* __restrict__ psy,
                                              const float* __restrict__ psz, int* __restrict__ idxb) {
    #pragma clang fp contract(off)
    int wid = threadIdx.x >> 6, lane = threadIdx.x & 63;
    int q = blockIdx.x * 4 + wid;                  // 0..4095
    int b = q >> 11;
    int base = b * NPT;
    float qx = psx[q], qy = psy[q], qz = psz[q];
    const float R2 = (float)(0.3 * 0.3);
    size_t ob = (size_t)q * NS;
    int cnt = 0, j0 = -1;
    unsigned long long below = (lane == 63) ? ~0ull >> 1 : ((1ull << (lane + 1)) - 1) >> 1;  // bits strictly below lane
    for (int c0 = 0; c0 < NPT; c0 += 64) {
        int j = c0 + lane;
        float dx = qx - psx[base + j];
        float dy = qy - psy[base + j];
        float dz = qz - psz[base + j];
        float d2 = dx * dx + dy * dy + dz * dz;
        bool hit = d2 < R2;
        unsigned long long m = __ballot(hit);
        if (m) {
            if (j0 < 0) j0 = c0 + __builtin_ctzll(m);
            int pos = cnt + __popcll(m & below);
            if (hit && pos < NS) idxb[ob + pos] = j;
            cnt += __popcll(m);
        }
        if (cnt >= NS) break;
    }
    if (lane >= cnt && lane < NS) idxb[ob + lane] = j0;
}

// K2 (MFMA): H = NF(65536x288) . Wbf^T(288x256), fused s=16 max/min/sum/sumsq epilogue.
__global__ __launch_bounds__(256) void k_mlp_mfma(const u16* __restrict__ ftbf, const u16* __restrict__ wbf,
                                                  const int* __restrict__ idxb, const float* __restrict__ ptsf,
                                                  float* __restrict__ Hmax, float* __restrict__ Hmin,
                                                  float* __restrict__ stats) {
    int bid = blockIdx.x;
    int nb = bid & 3, mb = bid >> 2;               // 4 consecutive blocks share A rows (L2 locality)
    int n0 = nb * 64;
    int w = threadIdx.x >> 6, lane = threadIdx.x & 63;
    int rbase = mb * 256 + w * 64;                 // wave's global row base (row = (b*N+n)*16+s)
    int b = rbase >> 15;
    int lg = lane >> 4, lr = lane & 15;

    size_t boff[4];
    #pragma unroll
    for (int ct = 0; ct < 4; ct++)
        boff[ct] = (size_t)(n0 + ct * 16 + lr) * KP2 + lg * 8;

    size_t aoff[4];
    uint4 lastA[4];
    #pragma unroll
    for (int rt = 0; rt < 4; rt++) {
        int row = rbase + rt * 16 + lr;
        int j = idxb[row];
        aoff[rt] = ((size_t)(b * NPT + j)) * CINF + (size_t)lg * 8;
        int pt = (rbase + rt * 16) >> 4;
        int n = pt & (NPT - 1);
        size_t cb = ((size_t)(b * NPT + n)) * 3;
        size_t jb = ((size_t)(b * NPT + j)) * 3;
        unsigned g0 = f2bf((ptsf[jb]     - ptsf[cb])     / 0.3f);
        unsigned g1 = f2bf((ptsf[jb + 1] - ptsf[cb + 1]) / 0.3f);
        unsigned g2 = f2bf((ptsf[jb + 2] - ptsf[cb + 2]) / 0.3f);
        uint4 la; la.x = 0u; la.y = 0u; la.z = 0u; la.w = 0u;
        if (lg == 0) { la.x = g0 | (g1 << 16); la.y = g2; }
        lastA[rt] = la;
    }

    f32x4 acc[4][4];
    #pragma unroll
    for (int rt = 0; rt < 4; rt++)
        #pragma unroll
        for (int ct = 0; ct < 4; ct++)
            acc[rt][ct] = (f32x4){0.f, 0.f, 0.f, 0.f};

    #pragma unroll
    for (int k0 = 0; k0 < 256; k0 += 32) {
        bf16x8 af[4], bfr[4];
        #pragma unroll
        for (int rt = 0; rt < 4; rt++)
            af[rt] = __builtin_bit_cast(bf16x8, *(const uint4*)(ftbf + aoff[rt] + k0));
        #pragma unroll
        for (int ct = 0; ct < 4; ct++)
            bfr[ct] = __builtin_bit_cast(bf16x8, *(const uint4*)(wbf + boff[ct] + k0));
        #pragma unroll
        for (int rt = 0; rt < 4; rt++)
            #pragma unroll
            for (int ct = 0; ct < 4; ct++)
                acc[rt][ct] = __builtin_amdgcn_mfma_f32_16x16x32_bf16(af[rt], bfr[ct], acc[rt][ct], 0, 0, 0);
    }
    {   // last K-step: cols 256..287 (coords)
        bf16x8 bfr[4];
        #pragma unroll
        for (int ct = 0; ct < 4; ct++)
            bfr[ct] = __builtin_bit_cast(bf16x8, *(const uint4*)(wbf + boff[ct] + 256));
        #pragma unroll
        for (int rt = 0; rt < 4; rt++) {
            bf16x8 af = __builtin_bit_cast(bf16x8, lastA[rt]);
            #pragma unroll
            for (int ct = 0; ct < 4; ct++)
                acc[rt][ct] = __builtin_amdgcn_mfma_f32_16x16x32_bf16(af, bfr[ct], acc[rt][ct], 0, 0, 0);
        }
    }

    float ssum[4] = {0.f, 0.f, 0.f, 0.f}, ssq[4] = {0.f, 0.f, 0.f, 0.f};
    #pragma unroll
    for (int rt = 0; rt < 4; rt++) {
        int pt = (rbase >> 4) + rt;
        #pragma unroll
        for (int ct = 0; ct < 4; ct++) {
            f32x4 a = acc[rt][ct];
            float mx = fmaxf(fmaxf(a.x, a.y), fmaxf(a.z, a.w));
            float mn = fminf(fminf(a.x, a.y), fminf(a.z, a.w));
            float sm = (a.x + a.y) + (a.z + a.w);
            float sq = (a.x * a.x + a.y * a.y) + (a.z * a.z + a.w * a.w);
            mx = fmaxf(mx, __shfl_xor(mx, 16)); mx = fmaxf(mx, __shfl_xor(mx, 32));
            mn = fminf(mn, __shfl_xor(mn, 16)); mn = fminf(mn, __shfl_xor(mn, 32));
            sm += __shfl_xor(sm, 16); sm += __shfl_xor(sm, 32);
            sq += __shfl_xor(sq, 16); sq += __shfl_xor(sq, 32);
            if (lane < 16) {
                int c = n0 + ct * 16 + lr;
                Hmax[(size_t)pt * C1 + c] = mx;
                Hmin[(size_t)pt * C1 + c] = mn;
            }
            ssum[ct] += sm; ssq[ct] += sq;
        }
    }
    #pragma unroll
    for (int ct = 0; ct < 4; ct++) {
        if (lane < 16) {
            int c = n0 + ct * 16 + lr;
            atomicAdd(&stats[c], ssum[ct]);
            atomicAdd(&stats[256 + c], ssq[ct]);
        }
    }
}

// K4: feats0 = max_s relu(BN(h)) via affine-monotone identity
__global__ void k_feats0(const float* __restrict__ Hmax, const float* __restrict__ Hmin,
                         const float* __restrict__ stats, const float* __restrict__ g,
                         const float* __restrict__ bt, float* __restrict__ f0) {
    int e = blockIdx.x * 256 + threadIdx.x;
    if (e >= NB * NPT * C1) return;
    int o = e & (C1 - 1);
    const float inv = 1.f / 65536.f;
    float m = stats[o] * inv;
    float var = fmaxf(stats[256 + o] * inv - m * m, 0.f);
    float a = g[o] / sqrtf(var + EPSF);
    float d = bt[o] - m * a;
    float h = (a > 0.f) ? Hmax[e] : Hmin[e];
    f0[e] = fmaxf(a * h + d, 0.f);
}

// K5/K7: out[bn][o] = X[bn][:] . W[o][:] + bias[o], accumulate BN stats
template<int K>
__global__ __launch_bounds__(128) void k_gemm(const float* __restrict__ X, const float* __restrict__ W,
                                              const float* __restrict__ bias, float* __restrict__ out,
                                              float* __restrict__ sum, float* __restrict__ sumsq) {
    __shared__ float xs[32][K];
    int row0 = blockIdx.x * 32;
    int tid = threadIdx.x;
    for (int k = tid; k < 32 * K; k += 128) {
        int r = k / K, c = k % K;
        xs[r][c] = X[(size_t)(row0 + r) * K + c];
    }
    __syncthreads();
    float acc[32];
    #pragma unroll
    for (int j = 0; j < 32; j++) acc[j] = 0.f;
    const float4* wp = (const float4*)(W + (size_t)tid * K);
    for (int c4 = 0; c4 < K / 4; c4++) {
        float4 w = wp[c4];
        #pragma unroll
        for (int j = 0; j < 32; j++) {
            float4 v = *(const float4*)&xs[j][c4 * 4];
            acc[j] += w.x * v.x + w.y * v.y + w.z * v.z + w.w * v.w;
        }
    }
    float bi = bias[tid];
    float s = 0.f, q = 0.f;
    #pragma unroll
    for (int j = 0; j < 32; j++) {
        float h = acc[j] + bi;
        out[(size_t)(row0 + j) * C2 + tid] = h;
        s += h; q += h * h;
    }
    atomicAdd(&sum[tid], s);
    atomicAdd(&sumsq[tid], q);
}

// K6: x = relu(BN(h)) (layer1)
__global__ void k_bnrelu(const float* __restrict__ h, const float* __restrict__ sum,
                         const float* __restrict__ sumsq, const float* __restrict__ g,
                         const float* __restrict__ bt, float* __restrict__ out) {
    int e = blockIdx.x * 256 + threadIdx.x;
    if (e >= NB * NPT * C2) return;
    int o = e & (C2 - 1);
    const float inv = 1.f / 4096.f;
    float m = sum[o] * inv;
    float var = fmaxf(sumsq[o] * inv - m * m, 0.f);
    float a = g[o] / sqrtf(var + EPSF);
    float d = bt[o] - m * a;
    out[e] = fmaxf(a * h[e] + d, 0.f);
}

// K8: feats = relu(BN(h2)); write output 0 (B,C2,N) in detected dtype + f32 copy for pooling
__global__ void k_final(const float* __restrict__ h2, const float* __restrict__ sum,
                        const float* __restrict__ sumsq, const float* __restrict__ g,
                        const float* __restrict__ bt, float* __restrict__ fp,
                        void* __restrict__ out0, const int* __restrict__ flag) {
    int e = blockIdx.x * 256 + threadIdx.x;
    if (e >= NB * NPT * C2) return;
    int f = *flag;
    int o = e & (C2 - 1);
    int bn = e >> 7;
    int b = bn >> 11, n = bn & (NPT - 1);
    const float inv = 1.f / 4096.f;
    float m = sum[o] * inv;
    float var = fmaxf(sumsq[o] * inv - m * m, 0.f);
    float a = g[o] / sqrtf(var + EPSF);
    float d = bt[o] - m * a;
    float v = fmaxf(a * h2[e] + d, 0.f);
    fp[e] = v;
    size_t oi = ((size_t)(b * C2 + o)) * NPT + n;
    if (f) ((float*)out0)[oi] = v;
    else   ((unsigned short*)out0)[oi] = f2bf(v);
}

// K9: RoI voxel max-pool. One 64-thr block per (b,r); two channel halves; 40 KB LDS.
__global__ __launch_bounds__(64) void k_pool(const float* __restrict__ ptsf, const float* __restrict__ roisf,
                                             const float* __restrict__ fp, void* __restrict__ d_out,
                                             const int* __restrict__ flag) {
    #pragma clang fp contract(off)
    __shared__ float pooled[NVOX * 64];
    __shared__ int list[NPT];
    __shared__ int cnt;
    int f = *flag;
    int bid = blockIdx.x;
    int b = bid >> 7;
    int tid = threadIdx.x;
    if (tid == 0) cnt = 0;
    size_t rb = ((size_t)bid) * 7;
    float cx = roisf[rb], cy = roisf[rb + 1], cz = roisf[rb + 2];
    float hx = roisf[rb + 3] * 0.5f;
    float hy = roisf[rb + 4] * 0.5f;
    float hz = roisf[rb + 5] * 0.5f;
    float ry = roisf[rb + 6];
    float cf = (float)cos((double)ry);
    float sf = (float)sin((double)ry);
    __syncthreads();
    for (int n = tid; n < NPT; n += 64) {
        size_t pb = ((size_t)(b * NPT + n)) * 3;
        float rx  = ptsf[pb]     - cx;
        float ryy = ptsf[pb + 1] - cy;
        float rz  = ptsf[pb + 2] - cz;
        float lx = rx * cf + ryy * sf;
        float ly = -rx * sf + ryy * cf;
        if (fabsf(lx) < hx && fabsf(ly) < hy && fabsf(rz) < hz) {
            int vx = (int)fminf(fmaxf(floorf((lx + hx) / (2.f * hx) * 5.f), 0.f), 4.f);
            int vy = (int)fminf(fmaxf(floorf((ly + hy) / (2.f * hy) * 5.f), 0.f), 4.f);
            int vz = (int)fminf(fmaxf(floorf((rz + hz) / (2.f * hz) * 5.f), 0.f), 4.f);
            int vox = (vx * 5 + vy) * 5 + vz;
            int pos = atomicAdd(&cnt, 1);
            list[pos] = (vox << 16) | n;
        }
    }
    __syncthreads();
    int m = cnt;
    size_t ob = (size_t)524288 + (size_t)bid * (NVOX * C2);
    for (int half = 0; half < 2; half++) {
        for (int k = tid; k < NVOX * 64; k += 64) pooled[k] = 0.f;
        __syncthreads();
        int c = half * 64 + tid;
        for (int e = 0; e < m; e++) {
            int u = list[e];
            int n = u & 0xFFFF, vox = u >> 16;
            float v = fp[((size_t)(b * NPT + n)) * C2 + c];
            float* p = &pooled[vox * 64 + tid];
            *p = fmaxf(*p, v);
        }
        __syncthreads();
        for (int k = tid; k < NVOX * 64; k += 64) {
            int vox = k >> 6, cc = k & 63;
            size_t oi = ob + (size_t)vox * C2 + half * 64 + cc;
            float v = pooled[k];
            if (f) ((float*)d_out)[oi] = v;
            else   ((unsigned short*)d_out)[oi] = f2bf(v);
        }
        __syncthreads();
    }
}

extern "C" void kernel_launch(void* const* d_in, const int* in_sizes, int n_in,
                              void* d_out, int out_size, void* d_ws, size_t ws_size,
                              hipStream_t stream) {
    const void* pts  = d_in[0];
    const void* feat = d_in[1];
    const void* rois = d_in[2];
    const void* Wm   = d_in[3];
    const void* gm   = d_in[4];
    const void* btm  = d_in[5];
    const void* W1   = d_in[6];
    const void* b1   = d_in[7];
    const void* g1   = d_in[8];
    const void* bt1  = d_in[9];
    const void* W2   = d_in[10];
    const void* b2   = d_in[11];
    const void* g2   = d_in[12];
    const void* bt2  = d_in[13];

    float* ws     = (float*)d_ws;
    int*   flag   = (int*)ws;                  // @0
    float* ptsf   = ws + 16;
    float* roisf  = ws + 12304;
    float* params = ws + 14096;
    u16*   wbf    = (u16*)(ws + 64528);        // 256x288 bf16
    float* stats  = ws + 101392;
    int*   idxb   = (int*)(ws + 102416);
    u16*   ftbf   = (u16*)(ws + 167952);       // 2x2048x256 bf16
    float* Hmax   = ws + 1216528;
    float* Hmin   = ws + 2265104;
    float* f0     = ws + 167952;               // overlays ftbf (dead after MFMA)
    float* h1     = ws + 1216528;              // overlays Hmax (dead after feats0)
    float* x1     = ws + 1740816;
    float* h2     = ws + 2265104;              // overlays Hmin
    float* fp     = ws + 2789392;
    float* psx    = ws + 3313680;
    float* psy    = ws + 3317776;
    float* psz    = ws + 3321872;

    k_detect<<<1, 256, 0, stream>>>(Wm, flag);
    k_cvt<<<dim3(128, 12), 256, 0, stream>>>(pts, rois, gm, btm, W1, b1, g1, bt1,
                                             W2, b2, g2, bt2, ptsf, roisf, params, flag);
    k_soa<<<16, 256, 0, stream>>>(ptsf, psx, psy, psz);
    k_transpose<<<dim3(NPT / 32, CINF / 32, NB), dim3(32, 8), 0, stream>>>(feat, ftbf, flag);
    k_prep<<<292, 256, 0, stream>>>(Wm, wbf, stats, flag);
    k_knn2<<<NB * NPT / 4, 256, 0, stream>>>(psx, psy, psz, idxb);
    k_mlp_mfma<<<1024, 256, 0, stream>>>(ftbf, wbf, idxb, ptsf, Hmax, Hmin, stats);
    k_feats0<<<(NB * NPT * C1) / 256, 256, 0, stream>>>(Hmax, Hmin, stats, params + 0, params + 256, f0);
    k_gemm<256><<<(NB * NPT) / 32, 128, 0, stream>>>(f0, params + 512, params + 33280, h1, stats + 512, stats + 640);
    k_bnrelu<<<(NB * NPT * C2) / 256, 256, 0, stream>>>(h1, stats + 512, stats + 640, params + 33408, params + 33536, x1);
    k_gemm<128><<<(NB * NPT) / 32, 128, 0, stream>>>(x1, params + 33664, params + 50048, h2, stats + 768, stats + 896);
    k_final<<<(NB * NPT * C2) / 256, 256, 0, stream>>>(h2, stats + 768, stats + 896, params + 50176, params + 50304, fp, d_out, flag);
    k_pool<<<NB * NROI, 64, 0, stream>>>(ptsf, roisf, fp, d_out, flag);
}

// Round 7
// 248.616 us; speedup vs baseline: 4.5837x; 1.2971x over previous
//
#include <hip/hip_runtime.h>
#include <hip/hip_bf16.h>

typedef __hip_bfloat16 bf16;
typedef unsigned short u16;

#define NB   2
#define NPT  2048
#define NROI 128
#define CINF 256
#define NS   16
#define KDIM 259     // CIN + 3
#define KP2  288     // K padded to multiple of 32 for MFMA
#define C1   256     // mlp out channels
#define C2   128     // layer1/2 out channels
#define NVOX 125
#define EPSF 1e-5f

typedef __bf16 bf16x8 __attribute__((ext_vector_type(8)));
typedef float  f32x4  __attribute__((ext_vector_type(4)));

// flag-branched input load: inputs are either all-bf16 or all-f32 (runtime-detected)
__device__ __forceinline__ float ldin(const void* p, size_t i, int f32flag) {
    if (f32flag) return ((const float*)p)[i];
    unsigned short u = ((const unsigned short*)p)[i];
    return __uint_as_float(((unsigned)u) << 16);
}

// round-to-nearest-even f32 -> bf16 (matches numpy)
__device__ __forceinline__ unsigned short f2bf(float x) {
    unsigned u = __float_as_uint(x);
    u += 0x7FFFu + ((u >> 16) & 1u);
    return (unsigned short)(u >> 16);
}

// ---------------- ws layout (float units), total 3,325,968 f = 13.30 MB ----------------
// flag  @0        [16]
// ptsf  @16       [12288]
// roisf @12304    [1792]
// params@14096    [50432]  [gm 0|btm 256| w1bf(bf16) 512..16896 | w2bf(bf16) 16896..25088 |
//                           b1 33280|g1 33408|bt1 33536| b2 50048|g2 50176|bt2 50304]
// Wbf   @64528    [36864]  (256x288 bf16)
// stats @101392   [1024]
// idxb  @102416   [65536 ints]
// ftbf  @167952   [524288] (bf16 2x2048x256)  -- f0bf (bf16 4096x256) overlays after MFMA
// Hmax  @1216528  [1048576]  -- h1 (f32 4096x128) overlays; x1bf (bf16) @1740816
// Hmin  @2265104  [1048576]  -- h2 (f32) overlays; fp @2789392
// psx   @3313680  [4096]; psy @3317776 [4096]; psz @3321872 [4096]

// D0: detect input dtype
__global__ void k_detect(const void* __restrict__ Wm, int* __restrict__ flag) {
    __shared__ int f;
    int tid = threadIdx.x;
    if (tid == 0) f = 0;
    __syncthreads();
    #pragma unroll
    for (int r = 0; r < 4; r++) {
        unsigned short u = ((const unsigned short*)Wm)[r * 256 + tid];
        float v = __uint_as_float(((unsigned)u) << 16);
        if (!(fabsf(v) <= 1e4f)) atomicOr(&f, 1);
    }
    __syncthreads();
    if (tid == 0) *flag = f;
}

// D1: convert pts/rois/small params to f32 scratch (W1/W2 now handled by k_prep as bf16)
__global__ void k_cvt(const void* __restrict__ pts, const void* __restrict__ rois,
                      const void* __restrict__ gm, const void* __restrict__ btm,
                      const void* __restrict__ b1, const void* __restrict__ g1,
                      const void* __restrict__ bt1, const void* __restrict__ b2,
                      const void* __restrict__ g2, const void* __restrict__ bt2,
                      float* __restrict__ ptsf, float* __restrict__ roisf,
                      float* __restrict__ params, const int* __restrict__ flag) {
    int f = *flag;
    int e = blockIdx.x * 256 + threadIdx.x;
    const void* src; float* dst; int n;
    switch (blockIdx.y) {
        case 0:  src = pts; dst = ptsf;           n = NB * NPT * 3; break;
        case 1:  src = rois; dst = roisf;         n = NB * NROI * 7; break;
        case 2:  src = gm;  dst = params + 0;     n = 256; break;
        case 3:  src = btm; dst = params + 256;   n = 256; break;
        case 4:  src = b1;  dst = params + 33280; n = 128; break;
        case 5:  src = g1;  dst = params + 33408; n = 128; break;
        case 6:  src = bt1; dst = params + 33536; n = 128; break;
        case 7:  src = b2;  dst = params + 50048; n = 128; break;
        case 8:  src = g2;  dst = params + 50176; n = 128; break;
        default: src = bt2; dst = params + 50304; n = 128; break;
    }
    if (e < n) dst[e] = ldin(src, e, f);
}

// D2: split points into SoA for the coalesced ballot-scan knn
__global__ void k_soa(const float* __restrict__ ptsf, float* __restrict__ psx,
                      float* __restrict__ psy, float* __restrict__ psz) {
    int e = blockIdx.x * 256 + threadIdx.x;
    if (e < NB * NPT) {
        psx[e] = ptsf[e * 3 + 0];
        psy[e] = ptsf[e * 3 + 1];
        psz[e] = ptsf[e * 3 + 2];
    }
}

// K0a: transpose features (B,CIN,N) -> ftbf (B,N,CIN) bf16
__global__ void k_transpose(const void* __restrict__ feat, u16* __restrict__ ftbf,
                            const int* __restrict__ flag) {
    __shared__ float tile[32][33];
    int f = *flag;
    int b = blockIdx.z;
    int n0 = blockIdx.x * 32, c0 = blockIdx.y * 32;
    int tx = threadIdx.x, ty = threadIdx.y;  // 32x8
    #pragma unroll
    for (int d = 0; d < 4; d++) {
        int c = c0 + ty + d * 8;
        tile[ty + d * 8][tx] = ldin(feat, ((size_t)(b * CINF + c)) * NPT + n0 + tx, f);
    }
    __syncthreads();
    #pragma unroll
    for (int d = 0; d < 4; d++) {
        int n = n0 + ty + d * 8;
        ftbf[((size_t)(b * NPT + n)) * CINF + c0 + tx] = f2bf(tile[tx][ty + d * 8]);
    }
}

// K0b: repack W_mlp -> Wbf [256][288] bf16; zero stats; repack W1/W2 -> bf16
__global__ void k_prep(const void* __restrict__ Wm, const void* __restrict__ W1,
                       const void* __restrict__ W2, u16* __restrict__ wbf,
                       u16* __restrict__ w1bf, u16* __restrict__ w2bf,
                       float* __restrict__ stats, const int* __restrict__ flag) {
    int f = *flag;
    int e = blockIdx.x * 256 + threadIdx.x;
    if (e < 256 * KP2) {
        int o = e / KP2, k = e % KP2;
        float v = 0.f;
        if (k < 256)      v = ldin(Wm, (size_t)o * KDIM + 3 + k, f);
        else if (k < 259) v = ldin(Wm, (size_t)o * KDIM + (k - 256), f);
        wbf[e] = f2bf(v);
    } else if (e < 256 * KP2 + 1024) {
        stats[e - 256 * KP2] = 0.f;
    } else if (e < 256 * KP2 + 1024 + 32768) {
        int idx = e - (256 * KP2 + 1024);
        w1bf[idx] = f2bf(ldin(W1, idx, f));
    } else if (e < 256 * KP2 + 1024 + 32768 + 16384) {
        int idx = e - (256 * KP2 + 1024 + 32768);
        w2bf[idx] = f2bf(ldin(W2, idx, f));
    }
}

// K1: ball query, wave-per-query ballot scan.
__global__ __launch_bounds__(256) void k_knn2(const float* __restrict__ psx, const float* __restrict__ psy,
                                              const float* __restrict__ psz, int* __restrict__ idxb) {
    #pragma clang fp contract(off)
    int wid = threadIdx.x >> 6, lane = threadIdx.x & 63;
    int q = blockIdx.x * 4 + wid;                  // 0..4095
    int b = q >> 11;
    int base = b * NPT;
    float qx = psx[q], qy = psy[q], qz = psz[q];
    const float R2 = (float)(0.3 * 0.3);
    size_t ob = (size_t)q * NS;
    int cnt = 0, j0 = -1;
    unsigned long long below = (lane == 63) ? ~0ull >> 1 : ((1ull << (lane + 1)) - 1) >> 1;
    for (int c0 = 0; c0 < NPT; c0 += 64) {
        int j = c0 + lane;
        float dx = qx - psx[base + j];
        float dy = qy - psy[base + j];
        float dz = qz - psz[base + j];
        float d2 = dx * dx + dy * dy + dz * dz;
        bool hit = d2 < R2;
        unsigned long long m = __ballot(hit);
        if (m) {
            if (j0 < 0) j0 = c0 + __builtin_ctzll(m);
            int pos = cnt + __popcll(m & below);
            if (hit && pos < NS) idxb[ob + pos] = j;
            cnt += __popcll(m);
        }
        if (cnt >= NS) break;
    }
    if (lane >= cnt && lane < NS) idxb[ob + lane] = j0;
}

// K2 (MFMA): H = NF(65536x288) . Wbf^T(288x256), fused s=16 max/min/sum/sumsq epilogue.
__global__ __launch_bounds__(256) void k_mlp_mfma(const u16* __restrict__ ftbf, const u16* __restrict__ wbf,
                                                  const int* __restrict__ idxb, const float* __restrict__ ptsf,
                                                  float* __restrict__ Hmax, float* __restrict__ Hmin,
                                                  float* __restrict__ stats) {
    int bid = blockIdx.x;
    int nb = bid & 3, mb = bid >> 2;
    int n0 = nb * 64;
    int w = threadIdx.x >> 6, lane = threadIdx.x & 63;
    int rbase = mb * 256 + w * 64;
    int b = rbase >> 15;
    int lg = lane >> 4, lr = lane & 15;

    size_t boff[4];
    #pragma unroll
    for (int ct = 0; ct < 4; ct++)
        boff[ct] = (size_t)(n0 + ct * 16 + lr) * KP2 + lg * 8;

    size_t aoff[4];
    uint4 lastA[4];
    #pragma unroll
    for (int rt = 0; rt < 4; rt++) {
        int row = rbase + rt * 16 + lr;
        int j = idxb[row];
        aoff[rt] = ((size_t)(b * NPT + j)) * CINF + (size_t)lg * 8;
        int pt = (rbase + rt * 16) >> 4;
        int n = pt & (NPT - 1);
        size_t cb = ((size_t)(b * NPT + n)) * 3;
        size_t jb = ((size_t)(b * NPT + j)) * 3;
        unsigned g0 = f2bf((ptsf[jb]     - ptsf[cb])     / 0.3f);
        unsigned g1 = f2bf((ptsf[jb + 1] - ptsf[cb + 1]) / 0.3f);
        unsigned g2 = f2bf((ptsf[jb + 2] - ptsf[cb + 2]) / 0.3f);
        uint4 la; la.x = 0u; la.y = 0u; la.z = 0u; la.w = 0u;
        if (lg == 0) { la.x = g0 | (g1 << 16); la.y = g2; }
        lastA[rt] = la;
    }

    f32x4 acc[4][4];
    #pragma unroll
    for (int rt = 0; rt < 4; rt++)
        #pragma unroll
        for (int ct = 0; ct < 4; ct++)
            acc[rt][ct] = (f32x4){0.f, 0.f, 0.f, 0.f};

    #pragma unroll
    for (int k0 = 0; k0 < 256; k0 += 32) {
        bf16x8 af[4], bfr[4];
        #pragma unroll
        for (int rt = 0; rt < 4; rt++)
            af[rt] = __builtin_bit_cast(bf16x8, *(const uint4*)(ftbf + aoff[rt] + k0));
        #pragma unroll
        for (int ct = 0; ct < 4; ct++)
            bfr[ct] = __builtin_bit_cast(bf16x8, *(const uint4*)(wbf + boff[ct] + k0));
        #pragma unroll
        for (int rt = 0; rt < 4; rt++)
            #pragma unroll
            for (int ct = 0; ct < 4; ct++)
                acc[rt][ct] = __builtin_amdgcn_mfma_f32_16x16x32_bf16(af[rt], bfr[ct], acc[rt][ct], 0, 0, 0);
    }
    {   // last K-step: cols 256..287 (coords)
        bf16x8 bfr[4];
        #pragma unroll
        for (int ct = 0; ct < 4; ct++)
            bfr[ct] = __builtin_bit_cast(bf16x8, *(const uint4*)(wbf + boff[ct] + 256));
        #pragma unroll
        for (int rt = 0; rt < 4; rt++) {
            bf16x8 af = __builtin_bit_cast(bf16x8, lastA[rt]);
            #pragma unroll
            for (int ct = 0; ct < 4; ct++)
                acc[rt][ct] = __builtin_amdgcn_mfma_f32_16x16x32_bf16(af, bfr[ct], acc[rt][ct], 0, 0, 0);
        }
    }

    float ssum[4] = {0.f, 0.f, 0.f, 0.f}, ssq[4] = {0.f, 0.f, 0.f, 0.f};
    #pragma unroll
    for (int rt = 0; rt < 4; rt++) {
        int pt = (rbase >> 4) + rt;
        #pragma unroll
        for (int ct = 0; ct < 4; ct++) {
            f32x4 a = acc[rt][ct];
            float mx = fmaxf(fmaxf(a.x, a.y), fmaxf(a.z, a.w));
            float mn = fminf(fminf(a.x, a.y), fminf(a.z, a.w));
            float sm = (a.x + a.y) + (a.z + a.w);
            float sq = (a.x * a.x + a.y * a.y) + (a.z * a.z + a.w * a.w);
            mx = fmaxf(mx, __shfl_xor(mx, 16)); mx = fmaxf(mx, __shfl_xor(mx, 32));
            mn = fminf(mn, __shfl_xor(mn, 16)); mn = fminf(mn, __shfl_xor(mn, 32));
            sm += __shfl_xor(sm, 16); sm += __shfl_xor(sm, 32);
            sq += __shfl_xor(sq, 16); sq += __shfl_xor(sq, 32);
            if (lane < 16) {
                int c = n0 + ct * 16 + lr;
                Hmax[(size_t)pt * C1 + c] = mx;
                Hmin[(size_t)pt * C1 + c] = mn;
            }
            ssum[ct] += sm; ssq[ct] += sq;
        }
    }
    #pragma unroll
    for (int ct = 0; ct < 4; ct++) {
        if (lane < 16) {
            int c = n0 + ct * 16 + lr;
            atomicAdd(&stats[c], ssum[ct]);
            atomicAdd(&stats[256 + c], ssq[ct]);
        }
    }
}

// K4: feats0 = max_s relu(BN(h)) via affine-monotone identity; emit bf16 for MFMA tail
__global__ void k_feats0(const float* __restrict__ Hmax, const float* __restrict__ Hmin,
                         const float* __restrict__ stats, const float* __restrict__ g,
                         const float* __restrict__ bt, u16* __restrict__ f0bf) {
    int e = blockIdx.x * 256 + threadIdx.x;
    if (e >= NB * NPT * C1) return;
    int o = e & (C1 - 1);
    const float inv = 1.f / 65536.f;
    float m = stats[o] * inv;
    float var = fmaxf(stats[256 + o] * inv - m * m, 0.f);
    float a = g[o] / sqrtf(var + EPSF);
    float d = bt[o] - m * a;
    float h = (a > 0.f) ? Hmax[e] : Hmin[e];
    f0bf[e] = f2bf(fmaxf(a * h + d, 0.f));
}

// K5/K7 (MFMA): out(4096xC2) = Xbf(4096xK) . Wb^T(KxC2) + bias, fused BN-stat epilogue.
// Wave = 16 rows x 32 cols (1x2 tiles); block = 4 waves = 16x128; grid = 256 blocks = 1024 waves.
template<int K>
__global__ __launch_bounds__(256) void k_lin(const u16* __restrict__ Xbf, const u16* __restrict__ Wb,
                                             const float* __restrict__ bias, float* __restrict__ out,
                                             float* __restrict__ sum, float* __restrict__ sumsq) {
    int w = threadIdx.x >> 6, lane = threadIdx.x & 63;
    int lg = lane >> 4, lr = lane & 15;
    int rbase = blockIdx.x * 16;
    int c0 = w * 32;

    size_t aoff = (size_t)(rbase + lr) * K + lg * 8;
    size_t boff0 = (size_t)(c0 + lr) * K + lg * 8;
    size_t boff1 = (size_t)(c0 + 16 + lr) * K + lg * 8;

    f32x4 acc0 = (f32x4){0.f, 0.f, 0.f, 0.f};
    f32x4 acc1 = (f32x4){0.f, 0.f, 0.f, 0.f};
    #pragma unroll
    for (int k0 = 0; k0 < K; k0 += 32) {
        bf16x8 af = __builtin_bit_cast(bf16x8, *(const uint4*)(Xbf + aoff + k0));
        bf16x8 b0 = __builtin_bit_cast(bf16x8, *(const uint4*)(Wb + boff0 + k0));
        bf16x8 b1 = __builtin_bit_cast(bf16x8, *(const uint4*)(Wb + boff1 + k0));
        acc0 = __builtin_amdgcn_mfma_f32_16x16x32_bf16(af, b0, acc0, 0, 0, 0);
        acc1 = __builtin_amdgcn_mfma_f32_16x16x32_bf16(af, b1, acc1, 0, 0, 0);
    }

    #pragma unroll
    for (int ct = 0; ct < 2; ct++) {
        f32x4 a = ct ? acc1 : acc0;
        int col = c0 + ct * 16 + lr;
        float bi = bias[col];
        float s = 0.f, q = 0.f;
        #pragma unroll
        for (int r = 0; r < 4; r++) {
            float h = a[r] + bi;
            out[(size_t)(rbase + lg * 4 + r) * C2 + col] = h;
            s += h; q += h * h;
        }
        s += __shfl_xor(s, 16); s += __shfl_xor(s, 32);
        q += __shfl_xor(q, 16); q += __shfl_xor(q, 32);
        if (lane < 16) {
            atomicAdd(&sum[col], s);
            atomicAdd(&sumsq[col], q);
        }
    }
}

// K6: x = relu(BN(h)) (layer1) -> bf16 for the next MFMA
__global__ void k_bnrelu(const float* __restrict__ h, const float* __restrict__ sum,
                         const float* __restrict__ sumsq, const float* __restrict__ g,
                         const float* __restrict__ bt, u16* __restrict__ xbf) {
    int e = blockIdx.x * 256 + threadIdx.x;
    if (e >= NB * NPT * C2) return;
    int o = e & (C2 - 1);
    const float inv = 1.f / 4096.f;
    float m = sum[o] * inv;
    float var = fmaxf(sumsq[o] * inv - m * m, 0.f);
    float a = g[o] / sqrtf(var + EPSF);
    float d = bt[o] - m * a;
    xbf[e] = f2bf(fmaxf(a * h[e] + d, 0.f));
}

// K8: feats = relu(BN(h2)); write output 0 (B,C2,N) in detected dtype + f32 copy for pooling
__global__ void k_final(const float* __restrict__ h2, const float* __restrict__ sum,
                        const float* __restrict__ sumsq, const float* __restrict__ g,
                        const float* __restrict__ bt, float* __restrict__ fp,
                        void* __restrict__ out0, const int* __restrict__ flag) {
    int e = blockIdx.x * 256 + threadIdx.x;
    if (e >= NB * NPT * C2) return;
    int f = *flag;
    int o = e & (C2 - 1);
    int bn = e >> 7;
    int b = bn >> 11, n = bn & (NPT - 1);
    const float inv = 1.f / 4096.f;
    float m = sum[o] * inv;
    float var = fmaxf(sumsq[o] * inv - m * m, 0.f);
    float a = g[o] / sqrtf(var + EPSF);
    float d = bt[o] - m * a;
    float v = fmaxf(a * h2[e] + d, 0.f);
    fp[e] = v;
    size_t oi = ((size_t)(b * C2 + o)) * NPT + n;
    if (f) ((float*)out0)[oi] = v;
    else   ((unsigned short*)out0)[oi] = f2bf(v);
}

// K9: RoI voxel max-pool. One 64-thr block per (b,r); two channel halves; 40 KB LDS.
__global__ __launch_bounds__(64) void k_pool(const float* __restrict__ ptsf, const float* __restrict__ roisf,
                                             const float* __restrict__ fp, void* __restrict__ d_out,
                                             const int* __restrict__ flag) {
    #pragma clang fp contract(off)
    __shared__ float pooled[NVOX * 64];
    __shared__ int list[NPT];
    __shared__ int cnt;
    int f = *flag;
    int bid = blockIdx.x;
    int b = bid >> 7;
    int tid = threadIdx.x;
    if (tid == 0) cnt = 0;
    size_t rb = ((size_t)bid) * 7;
    float cx = roisf[rb], cy = roisf[rb + 1], cz = roisf[rb + 2];
    float hx = roisf[rb + 3] * 0.5f;
    float hy = roisf[rb + 4] * 0.5f;
    float hz = roisf[rb + 5] * 0.5f;
    float ry = roisf[rb + 6];
    float cf = (float)cos((double)ry);
    float sf = (float)sin((double)ry);
    __syncthreads();
    for (int n = tid; n < NPT; n += 64) {
        size_t pb = ((size_t)(b * NPT + n)) * 3;
        float rx  = ptsf[pb]     - cx;
        float ryy = ptsf[pb + 1] - cy;
        float rz  = ptsf[pb + 2] - cz;
        float lx = rx * cf + ryy * sf;
        float ly = -rx * sf + ryy * cf;
        if (fabsf(lx) < hx && fabsf(ly) < hy && fabsf(rz) < hz) {
            int vx = (int)fminf(fmaxf(floorf((lx + hx) / (2.f * hx) * 5.f), 0.f), 4.f);
            int vy = (int)fminf(fmaxf(floorf((ly + hy) / (2.f * hy) * 5.f), 0.f), 4.f);
            int vz = (int)fminf(fmaxf(floorf((rz + hz) / (2.f * hz) * 5.f), 0.f), 4.f);
            int vox = (vx * 5 + vy) * 5 + vz;
            int pos = atomicAdd(&cnt, 1);
            list[pos] = (vox << 16) | n;
        }
    }
    __syncthreads();
    int m = cnt;
    size_t ob = (size_t)524288 + (size_t)bid * (NVOX * C2);
    for (int half = 0; half < 2; half++) {
        for (int k = tid; k < NVOX * 64; k += 64) pooled[k] = 0.f;
        __syncthreads();
        int c = half * 64 + tid;
        for (int e = 0; e < m; e++) {
            int u = list[e];
            int n = u & 0xFFFF, vox = u >> 16;
            float v = fp[((size_t)(b * NPT + n)) * C2 + c];
            float* p = &pooled[vox * 64 + tid];
            *p = fmaxf(*p, v);
        }
        __syncthreads();
        for (int k = tid; k < NVOX * 64; k += 64) {
            int vox = k >> 6, cc = k & 63;
            size_t oi = ob + (size_t)vox * C2 + half * 64 + cc;
            float v = pooled[k];
            if (f) ((float*)d_out)[oi] = v;
            else   ((unsigned short*)d_out)[oi] = f2bf(v);
        }
        __syncthreads();
    }
}

extern "C" void kernel_launch(void* const* d_in, const int* in_sizes, int n_in,
                              void* d_out, int out_size, void* d_ws, size_t ws_size,
                              hipStream_t stream) {
    const void* pts  = d_in[0];
    const void* feat = d_in[1];
    const void* rois = d_in[2];
    const void* Wm   = d_in[3];
    const void* gm   = d_in[4];
    const void* btm  = d_in[5];
    const void* W1   = d_in[6];
    const void* b1   = d_in[7];
    const void* g1   = d_in[8];
    const void* bt1  = d_in[9];
    const void* W2   = d_in[10];
    const void* b2   = d_in[11];
    const void* g2   = d_in[12];
    const void* bt2  = d_in[13];

    float* ws     = (float*)d_ws;
    int*   flag   = (int*)ws;                  // @0
    float* ptsf   = ws + 16;
    float* roisf  = ws + 12304;
    float* params = ws + 14096;
    u16*   w1bf   = (u16*)(params + 512);      // 128x256 bf16 (old f32-W1 slot)
    u16*   w2bf   = (u16*)(params + 512 + 16384); // 128x128 bf16
    u16*   wbf    = (u16*)(ws + 64528);        // 256x288 bf16
    float* stats  = ws + 101392;
    int*   idxb   = (int*)(ws + 102416);
    u16*   ftbf   = (u16*)(ws + 167952);       // 2x2048x256 bf16
    float* Hmax   = ws + 1216528;
    float* Hmin   = ws + 2265104;
    u16*   f0bf   = (u16*)(ws + 167952);       // overlays ftbf (dead after MFMA)
    float* h1     = ws + 1216528;              // overlays Hmax (dead after feats0)
    u16*   x1bf   = (u16*)(ws + 1740816);
    float* h2     = ws + 2265104;              // overlays Hmin
    float* fp     = ws + 2789392;
    float* psx    = ws + 3313680;
    float* psy    = ws + 3317776;
    float* psz    = ws + 3321872;

    k_detect<<<1, 256, 0, stream>>>(Wm, flag);
    k_cvt<<<dim3(48, 10), 256, 0, stream>>>(pts, rois, gm, btm, b1, g1, bt1, b2, g2, bt2,
                                            ptsf, roisf, params, flag);
    k_soa<<<16, 256, 0, stream>>>(ptsf, psx, psy, psz);
    k_transpose<<<dim3(NPT / 32, CINF / 32, NB), dim3(32, 8), 0, stream>>>(feat, ftbf, flag);
    k_prep<<<484, 256, 0, stream>>>(Wm, W1, W2, wbf, w1bf, w2bf, stats, flag);
    k_knn2<<<NB * NPT / 4, 256, 0, stream>>>(psx, psy, psz, idxb);
    k_mlp_mfma<<<1024, 256, 0, stream>>>(ftbf, wbf, idxb, ptsf, Hmax, Hmin, stats);
    k_feats0<<<(NB * NPT * C1) / 256, 256, 0, stream>>>(Hmax, Hmin, stats, params + 0, params + 256, f0bf);
    k_lin<256><<<256, 256, 0, stream>>>(f0bf, w1bf, params + 33280, h1, stats + 512, stats + 640);
    k_bnrelu<<<(NB * NPT * C2) / 256, 256, 0, stream>>>(h1, stats + 512, stats + 640, params + 33408, params + 33536, x1bf);
    k_lin<128><<<256, 256, 0, stream>>>(x1bf, w2bf, params + 50048, h2, stats + 768, stats + 896);
    k_final<<<(NB * NPT * C2) / 256, 256, 0, stream>>>(h2, stats + 768, stats + 896, params + 50176, params + 50304, fp, d_out, flag);
    k_pool<<<NB * NROI, 64, 0, stream>>>(ptsf, roisf, fp, d_out, flag);
}

// Round 8
// 225.455 us; speedup vs baseline: 5.0546x; 1.1027x over previous
//
#include <hip/hip_runtime.h>
#include <hip/hip_bf16.h>

typedef __hip_bfloat16 bf16;
typedef unsigned short u16;

#define NB   2
#define NPT  2048
#define NROI 128
#define CINF 256
#define NS   16
#define KDIM 259     // CIN + 3
#define KP2  288     // W_mlp repack stride (cols 0..255 feat, 256..258 xyz, pad)
#define C1   256     // mlp out channels
#define C2   128     // layer1/2 out channels
#define NVOX 125
#define EPSF 1e-5f

typedef __bf16 bf16x8 __attribute__((ext_vector_type(8)));
typedef float  f32x4  __attribute__((ext_vector_type(4)));

// flag-branched input load: inputs are either all-bf16 or all-f32 (runtime-detected)
__device__ __forceinline__ float ldin(const void* p, size_t i, int f32flag) {
    if (f32flag) return ((const float*)p)[i];
    unsigned short u = ((const unsigned short*)p)[i];
    return __uint_as_float(((unsigned)u) << 16);
}

// round-to-nearest-even f32 -> bf16 (matches numpy)
__device__ __forceinline__ unsigned short f2bf(float x) {
    unsigned u = __float_as_uint(x);
    u += 0x7FFFu + ((u >> 16) & 1u);
    return (unsigned short)(u >> 16);
}

// ---------------- ws layout (float units), total 4,374,544 f = 17.5 MB ----------------
// flag  @0        [16]
// ptsf  @16       [12288]
// roisf @12304    [1792]
// params@14096    [50432]  [gm 0|btm 256| w1bf(bf16) 512..16896 | w2bf(bf16) 16896..25088 |
//                           wxyz 25088..25856 | b1 33280|g1 33408|bt1 33536| b2 50048|g2 50176|bt2 50304]
// Wbf   @64528    [36864]  (256x288 bf16)
// stats @101392   [1024]
// idxb  @102416   [65536 ints]
// ftbf  @167952   [524288] (bf16 2x2048x256)  -- f0bf overlays after k_gather
// Hmax  @1216528  [1048576]  -- h1 overlays; x1bf @1740816
// Hmin  @2265104  [1048576]  -- h2 overlays; fp @2789392
// psx   @3313680  [4096]; psy @3317776 [4096]; psz @3321872 [4096]
// Hf    @3325968  [1048576]  (f32 4096x256 dense feature-MLP output)

// D0: detect input dtype
__global__ void k_detect(const void* __restrict__ Wm, int* __restrict__ flag) {
    __shared__ int f;
    int tid = threadIdx.x;
    if (tid == 0) f = 0;
    __syncthreads();
    #pragma unroll
    for (int r = 0; r < 4; r++) {
        unsigned short u = ((const unsigned short*)Wm)[r * 256 + tid];
        float v = __uint_as_float(((unsigned)u) << 16);
        if (!(fabsf(v) <= 1e4f)) atomicOr(&f, 1);
    }
    __syncthreads();
    if (tid == 0) *flag = f;
}

// D1: convert pts/rois/small params to f32 scratch; case 10 extracts W_xyz [3][256]
__global__ void k_cvt(const void* __restrict__ pts, const void* __restrict__ rois,
                      const void* __restrict__ gm, const void* __restrict__ btm,
                      const void* __restrict__ b1, const void* __restrict__ g1,
                      const void* __restrict__ bt1, const void* __restrict__ b2,
                      const void* __restrict__ g2, const void* __restrict__ bt2,
                      const void* __restrict__ Wm,
                      float* __restrict__ ptsf, float* __restrict__ roisf,
                      float* __restrict__ params, const int* __restrict__ flag) {
    int f = *flag;
    int e = blockIdx.x * 256 + threadIdx.x;
    if (blockIdx.y == 10) {   // wxyz[d*256+o] = Wm[o*KDIM+d]
        if (e < 768) {
            int d = e >> 8, o = e & 255;
            params[25088 + e] = ldin(Wm, (size_t)o * KDIM + d, f);
        }
        return;
    }
    const void* src; float* dst; int n;
    switch (blockIdx.y) {
        case 0:  src = pts; dst = ptsf;           n = NB * NPT * 3; break;
        case 1:  src = rois; dst = roisf;         n = NB * NROI * 7; break;
        case 2:  src = gm;  dst = params + 0;     n = 256; break;
        case 3:  src = btm; dst = params + 256;   n = 256; break;
        case 4:  src = b1;  dst = params + 33280; n = 128; break;
        case 5:  src = g1;  dst = params + 33408; n = 128; break;
        case 6:  src = bt1; dst = params + 33536; n = 128; break;
        case 7:  src = b2;  dst = params + 50048; n = 128; break;
        case 8:  src = g2;  dst = params + 50176; n = 128; break;
        default: src = bt2; dst = params + 50304; n = 128; break;
    }
    if (e < n) dst[e] = ldin(src, e, f);
}

// D2: split points into SoA for the coalesced ballot-scan knn
__global__ void k_soa(const float* __restrict__ ptsf, float* __restrict__ psx,
                      float* __restrict__ psy, float* __restrict__ psz) {
    int e = blockIdx.x * 256 + threadIdx.x;
    if (e < NB * NPT) {
        psx[e] = ptsf[e * 3 + 0];
        psy[e] = ptsf[e * 3 + 1];
        psz[e] = ptsf[e * 3 + 2];
    }
}

// K0a: transpose features (B,CIN,N) -> ftbf (B,N,CIN) bf16
__global__ void k_transpose(const void* __restrict__ feat, u16* __restrict__ ftbf,
                            const int* __restrict__ flag) {
    __shared__ float tile[32][33];
    int f = *flag;
    int b = blockIdx.z;
    int n0 = blockIdx.x * 32, c0 = blockIdx.y * 32;
    int tx = threadIdx.x, ty = threadIdx.y;  // 32x8
    #pragma unroll
    for (int d = 0; d < 4; d++) {
        int c = c0 + ty + d * 8;
        tile[ty + d * 8][tx] = ldin(feat, ((size_t)(b * CINF + c)) * NPT + n0 + tx, f);
    }
    __syncthreads();
    #pragma unroll
    for (int d = 0; d < 4; d++) {
        int n = n0 + ty + d * 8;
        ftbf[((size_t)(b * NPT + n)) * CINF + c0 + tx] = f2bf(tile[tx][ty + d * 8]);
    }
}

// K0b: repack W_mlp -> Wbf [256][288] bf16; zero stats; repack W1/W2 -> bf16
__global__ void k_prep(const void* __restrict__ Wm, const void* __restrict__ W1,
                       const void* __restrict__ W2, u16* __restrict__ wbf,
                       u16* __restrict__ w1bf, u16* __restrict__ w2bf,
                       float* __restrict__ stats, const int* __restrict__ flag) {
    int f = *flag;
    int e = blockIdx.x * 256 + threadIdx.x;
    if (e < 256 * KP2) {
        int o = e / KP2, k = e % KP2;
        float v = 0.f;
        if (k < 256)      v = ldin(Wm, (size_t)o * KDIM + 3 + k, f);
        else if (k < 259) v = ldin(Wm, (size_t)o * KDIM + (k - 256), f);
        wbf[e] = f2bf(v);
    } else if (e < 256 * KP2 + 1024) {
        stats[e - 256 * KP2] = 0.f;
    } else if (e < 256 * KP2 + 1024 + 32768) {
        int idx = e - (256 * KP2 + 1024);
        w1bf[idx] = f2bf(ldin(W1, idx, f));
    } else if (e < 256 * KP2 + 1024 + 32768 + 16384) {
        int idx = e - (256 * KP2 + 1024 + 32768);
        w2bf[idx] = f2bf(ldin(W2, idx, f));
    }
}

// K1: ball query, wave-per-query ballot scan.
__global__ __launch_bounds__(256) void k_knn2(const float* __restrict__ psx, const float* __restrict__ psy,
                                              const float* __restrict__ psz, int* __restrict__ idxb) {
    #pragma clang fp contract(off)
    int wid = threadIdx.x >> 6, lane = threadIdx.x & 63;
    int q = blockIdx.x * 4 + wid;                  // 0..4095
    int b = q >> 11;
    int base = b * NPT;
    float qx = psx[q], qy = psy[q], qz = psz[q];
    const float R2 = (float)(0.3 * 0.3);
    size_t ob = (size_t)q * NS;
    int cnt = 0, j0 = -1;
    unsigned long long below = (lane == 63) ? ~0ull >> 1 : ((1ull << (lane + 1)) - 1) >> 1;
    for (int c0 = 0; c0 < NPT; c0 += 64) {
        int j = c0 + lane;
        float dx = qx - psx[base + j];
        float dy = qy - psy[base + j];
        float dz = qz - psz[base + j];
        float d2 = dx * dx + dy * dy + dz * dz;
        bool hit = d2 < R2;
        unsigned long long m = __ballot(hit);
        if (m) {
            if (j0 < 0) j0 = c0 + __builtin_ctzll(m);
            int pos = cnt + __popcll(m & below);
            if (hit && pos < NS) idxb[ob + pos] = j;
            cnt += __popcll(m);
        }
        if (cnt >= NS) break;
    }
    if (lane >= cnt && lane < NS) idxb[ob + lane] = j0;
}

// K2a (dense MFMA): Hf[4096x256] = ftbf(4096x256) . W_feat^T. Wave = 16 rows x 32 cols.
__global__ __launch_bounds__(256) void k_dense(const u16* __restrict__ ftbf, const u16* __restrict__ wbf,
                                               float* __restrict__ Hf) {
    int w = threadIdx.x >> 6, lane = threadIdx.x & 63;
    int lg = lane >> 4, lr = lane & 15;
    int rbase = blockIdx.x * 16;
    int c0 = blockIdx.y * 128 + w * 32;

    size_t aoff  = (size_t)(rbase + lr) * CINF + lg * 8;
    size_t boff0 = (size_t)(c0 + lr) * KP2 + lg * 8;
    size_t boff1 = (size_t)(c0 + 16 + lr) * KP2 + lg * 8;

    f32x4 acc0 = (f32x4){0.f, 0.f, 0.f, 0.f};
    f32x4 acc1 = (f32x4){0.f, 0.f, 0.f, 0.f};
    #pragma unroll
    for (int k0 = 0; k0 < 256; k0 += 32) {
        bf16x8 af = __builtin_bit_cast(bf16x8, *(const uint4*)(ftbf + aoff + k0));
        bf16x8 b0 = __builtin_bit_cast(bf16x8, *(const uint4*)(wbf + boff0 + k0));
        bf16x8 b1 = __builtin_bit_cast(bf16x8, *(const uint4*)(wbf + boff1 + k0));
        acc0 = __builtin_amdgcn_mfma_f32_16x16x32_bf16(af, b0, acc0, 0, 0, 0);
        acc1 = __builtin_amdgcn_mfma_f32_16x16x32_bf16(af, b1, acc1, 0, 0, 0);
    }
    #pragma unroll
    for (int r = 0; r < 4; r++) {
        int row = rbase + lg * 4 + r;
        Hf[(size_t)row * C1 + c0 + lr] = acc0[r];
        Hf[(size_t)row * C1 + c0 + 16 + lr] = acc1[r];
    }
}

// K2b (gather-reduce): per point, h[s,o] = Hf[j_s][o] + W_xyz[o].gx(s); keep max/min over s
// + BN-stat partials. 256 thr = 256 channels; GPTS points per block; fully coalesced Hf rows.
#define GPTS 8
__global__ __launch_bounds__(256) void k_gather(const float* __restrict__ Hf, const int* __restrict__ idxb,
                                                const float* __restrict__ ptsf, const float* __restrict__ wxyz,
                                                float* __restrict__ Hmax, float* __restrict__ Hmin,
                                                float* __restrict__ stats) {
    __shared__ int   lj[NS];
    __shared__ float lgx[NS], lgy[NS], lgz[NS];
    int o = threadIdx.x;
    float wx = wxyz[o], wy = wxyz[256 + o], wz = wxyz[512 + o];
    float ssum = 0.f, ssq = 0.f;
    for (int p = 0; p < GPTS; p++) {
        int pt = blockIdx.x * GPTS + p;
        int b = pt >> 11;
        int base = b * NPT;
        if (o < NS) {
            int j = idxb[(size_t)pt * NS + o];
            lj[o] = j;
            size_t jb = ((size_t)(base + j)) * 3;
            size_t cb = (size_t)pt * 3;
            lgx[o] = (ptsf[jb]     - ptsf[cb])     / 0.3f;
            lgy[o] = (ptsf[jb + 1] - ptsf[cb + 1]) / 0.3f;
            lgz[o] = (ptsf[jb + 2] - ptsf[cb + 2]) / 0.3f;
        }
        __syncthreads();
        float mx = -3.4e38f, mn = 3.4e38f;
        #pragma unroll
        for (int s = 0; s < NS; s++) {
            float v = Hf[(size_t)(base + lj[s]) * C1 + o] + wx * lgx[s] + wy * lgy[s] + wz * lgz[s];
            mx = fmaxf(mx, v); mn = fminf(mn, v);
            ssum += v; ssq += v * v;
        }
        Hmax[(size_t)pt * C1 + o] = mx;
        Hmin[(size_t)pt * C1 + o] = mn;
        __syncthreads();
    }
    atomicAdd(&stats[o], ssum);
    atomicAdd(&stats[256 + o], ssq);
}

// K4: feats0 = max_s relu(BN(h)) via affine-monotone identity; emit bf16 for MFMA tail
__global__ void k_feats0(const float* __restrict__ Hmax, const float* __restrict__ Hmin,
                         const float* __restrict__ stats, const float* __restrict__ g,
                         const float* __restrict__ bt, u16* __restrict__ f0bf) {
    int e = blockIdx.x * 256 + threadIdx.x;
    if (e >= NB * NPT * C1) return;
    int o = e & (C1 - 1);
    const float inv = 1.f / 65536.f;
    float m = stats[o] * inv;
    float var = fmaxf(stats[256 + o] * inv - m * m, 0.f);
    float a = g[o] / sqrtf(var + EPSF);
    float d = bt[o] - m * a;
    float h = (a > 0.f) ? Hmax[e] : Hmin[e];
    f0bf[e] = f2bf(fmaxf(a * h + d, 0.f));
}

// K5/K7 (MFMA): out(4096xC2) = Xbf(4096xK) . Wb^T(KxC2) + bias, fused BN-stat epilogue.
template<int K>
__global__ __launch_bounds__(256) void k_lin(const u16* __restrict__ Xbf, const u16* __restrict__ Wb,
                                             const float* __restrict__ bias, float* __restrict__ out,
                                             float* __restrict__ sum, float* __restrict__ sumsq) {
    int w = threadIdx.x >> 6, lane = threadIdx.x & 63;
    int lg = lane >> 4, lr = lane & 15;
    int rbase = blockIdx.x * 16;
    int c0 = w * 32;

    size_t aoff = (size_t)(rbase + lr) * K + lg * 8;
    size_t boff0 = (size_t)(c0 + lr) * K + lg * 8;
    size_t boff1 = (size_t)(c0 + 16 + lr) * K + lg * 8;

    f32x4 acc0 = (f32x4){0.f, 0.f, 0.f, 0.f};
    f32x4 acc1 = (f32x4){0.f, 0.f, 0.f, 0.f};
    #pragma unroll
    for (int k0 = 0; k0 < K; k0 += 32) {
        bf16x8 af = __builtin_bit_cast(bf16x8, *(const uint4*)(Xbf + aoff + k0));
        bf16x8 b0 = __builtin_bit_cast(bf16x8, *(const uint4*)(Wb + boff0 + k0));
        bf16x8 b1 = __builtin_bit_cast(bf16x8, *(const uint4*)(Wb + boff1 + k0));
        acc0 = __builtin_amdgcn_mfma_f32_16x16x32_bf16(af, b0, acc0, 0, 0, 0);
        acc1 = __builtin_amdgcn_mfma_f32_16x16x32_bf16(af, b1, acc1, 0, 0, 0);
    }

    #pragma unroll
    for (int ct = 0; ct < 2; ct++) {
        f32x4 a = ct ? acc1 : acc0;
        int col = c0 + ct * 16 + lr;
        float bi = bias[col];
        float s = 0.f, q = 0.f;
        #pragma unroll
        for (int r = 0; r < 4; r++) {
            float h = a[r] + bi;
            out[(size_t)(rbase + lg * 4 + r) * C2 + col] = h;
            s += h; q += h * h;
        }
        s += __shfl_xor(s, 16); s += __shfl_xor(s, 32);
        q += __shfl_xor(q, 16); q += __shfl_xor(q, 32);
        if (lane < 16) {
            atomicAdd(&sum[col], s);
            atomicAdd(&sumsq[col], q);
        }
    }
}

// K6: x = relu(BN(h)) (layer1) -> bf16 for the next MFMA
__global__ void k_bnrelu(const float* __restrict__ h, const float* __restrict__ sum,
                         const float* __restrict__ sumsq, const float* __restrict__ g,
                         const float* __restrict__ bt, u16* __restrict__ xbf) {
    int e = blockIdx.x * 256 + threadIdx.x;
    if (e >= NB * NPT * C2) return;
    int o = e & (C2 - 1);
    const float inv = 1.f / 4096.f;
    float m = sum[o] * inv;
    float var = fmaxf(sumsq[o] * inv - m * m, 0.f);
    float a = g[o] / sqrtf(var + EPSF);
    float d = bt[o] - m * a;
    xbf[e] = f2bf(fmaxf(a * h[e] + d, 0.f));
}

// K8: feats = relu(BN(h2)); write output 0 (B,C2,N) in detected dtype + f32 copy for pooling
__global__ void k_final(const float* __restrict__ h2, const float* __restrict__ sum,
                        const float* __restrict__ sumsq, const float* __restrict__ g,
                        const float* __restrict__ bt, float* __restrict__ fp,
                        void* __restrict__ out0, const int* __restrict__ flag) {
    int e = blockIdx.x * 256 + threadIdx.x;
    if (e >= NB * NPT * C2) return;
    int f = *flag;
    int o = e & (C2 - 1);
    int bn = e >> 7;
    int b = bn >> 11, n = bn & (NPT - 1);
    const float inv = 1.f / 4096.f;
    float m = sum[o] * inv;
    float var = fmaxf(sumsq[o] * inv - m * m, 0.f);
    float a = g[o] / sqrtf(var + EPSF);
    float d = bt[o] - m * a;
    float v = fmaxf(a * h2[e] + d, 0.f);
    fp[e] = v;
    size_t oi = ((size_t)(b * C2 + o)) * NPT + n;
    if (f) ((float*)out0)[oi] = v;
    else   ((unsigned short*)out0)[oi] = f2bf(v);
}

// K9: RoI voxel max-pool. One 64-thr block per (b,r); two channel halves; 40 KB LDS.
__global__ __launch_bounds__(64) void k_pool(const float* __restrict__ ptsf, const float* __restrict__ roisf,
                                             const float* __restrict__ fp, void* __restrict__ d_out,
                                             const int* __restrict__ flag) {
    #pragma clang fp contract(off)
    __shared__ float pooled[NVOX * 64];
    __shared__ int list[NPT];
    __shared__ int cnt;
    int f = *flag;
    int bid = blockIdx.x;
    int b = bid >> 7;
    int tid = threadIdx.x;
    if (tid == 0) cnt = 0;
    size_t rb = ((size_t)bid) * 7;
    float cx = roisf[rb], cy = roisf[rb + 1], cz = roisf[rb + 2];
    float hx = roisf[rb + 3] * 0.5f;
    float hy = roisf[rb + 4] * 0.5f;
    float hz = roisf[rb + 5] * 0.5f;
    float ry = roisf[rb + 6];
    float cf = (float)cos((double)ry);
    float sf = (float)sin((double)ry);
    __syncthreads();
    for (int n = tid; n < NPT; n += 64) {
        size_t pb = ((size_t)(b * NPT + n)) * 3;
        float rx  = ptsf[pb]     - cx;
        float ryy = ptsf[pb + 1] - cy;
        float rz  = ptsf[pb + 2] - cz;
        float lx = rx * cf + ryy * sf;
        float ly = -rx * sf + ryy * cf;
        if (fabsf(lx) < hx && fabsf(ly) < hy && fabsf(rz) < hz) {
            int vx = (int)fminf(fmaxf(floorf((lx + hx) / (2.f * hx) * 5.f), 0.f), 4.f);
            int vy = (int)fminf(fmaxf(floorf((ly + hy) / (2.f * hy) * 5.f), 0.f), 4.f);
            int vz = (int)fminf(fmaxf(floorf((rz + hz) / (2.f * hz) * 5.f), 0.f), 4.f);
            int vox = (vx * 5 + vy) * 5 + vz;
            int pos = atomicAdd(&cnt, 1);
            list[pos] = (vox << 16) | n;
        }
    }
    __syncthreads();
    int m = cnt;
    size_t ob = (size_t)524288 + (size_t)bid * (NVOX * C2);
    for (int half = 0; half < 2; half++) {
        for (int k = tid; k < NVOX * 64; k += 64) pooled[k] = 0.f;
        __syncthreads();
        int c = half * 64 + tid;
        for (int e = 0; e < m; e++) {
            int u = list[e];
            int n = u & 0xFFFF, vox = u >> 16;
            float v = fp[((size_t)(b * NPT + n)) * C2 + c];
            float* p = &pooled[vox * 64 + tid];
            *p = fmaxf(*p, v);
        }
        __syncthreads();
        for (int k = tid; k < NVOX * 64; k += 64) {
            int vox = k >> 6, cc = k & 63;
            size_t oi = ob + (size_t)vox * C2 + half * 64 + cc;
            float v = pooled[k];
            if (f) ((float*)d_out)[oi] = v;
            else   ((unsigned short*)d_out)[oi] = f2bf(v);
        }
        __syncthreads();
    }
}

extern "C" void kernel_launch(void* const* d_in, const int* in_sizes, int n_in,
                              void* d_out, int out_size, void* d_ws, size_t ws_size,
                              hipStream_t stream) {
    const void* pts  = d_in[0];
    const void* feat = d_in[1];
    const void* rois = d_in[2];
    const void* Wm   = d_in[3];
    const void* gm   = d_in[4];
    const void* btm  = d_in[5];
    const void* W1   = d_in[6];
    const void* b1   = d_in[7];
    const void* g1   = d_in[8];
    const void* bt1  = d_in[9];
    const void* W2   = d_in[10];
    const void* b2   = d_in[11];
    const void* g2   = d_in[12];
    const void* bt2  = d_in[13];

    float* ws     = (float*)d_ws;
    int*   flag   = (int*)ws;                  // @0
    float* ptsf   = ws + 16;
    float* roisf  = ws + 12304;
    float* params = ws + 14096;
    u16*   w1bf   = (u16*)(params + 512);
    u16*   w2bf   = (u16*)(params + 512 + 16384);
    float* wxyz   = params + 25088;            // [3][256] f32
    u16*   wbf    = (u16*)(ws + 64528);        // 256x288 bf16
    float* stats  = ws + 101392;
    int*   idxb   = (int*)(ws + 102416);
    u16*   ftbf   = (u16*)(ws + 167952);       // 2x2048x256 bf16
    float* Hmax   = ws + 1216528;
    float* Hmin   = ws + 2265104;
    u16*   f0bf   = (u16*)(ws + 167952);       // overlays ftbf (dead after k_dense)
    float* h1     = ws + 1216528;              // overlays Hmax (dead after feats0)
    u16*   x1bf   = (u16*)(ws + 1740816);
    float* h2     = ws + 2265104;              // overlays Hmin
    float* fp     = ws + 2789392;
    float* psx    = ws + 3313680;
    float* psy    = ws + 3317776;
    float* psz    = ws + 3321872;
    float* Hf     = ws + 3325968;              // f32 4096x256

    k_detect<<<1, 256, 0, stream>>>(Wm, flag);
    k_cvt<<<dim3(48, 11), 256, 0, stream>>>(pts, rois, gm, btm, b1, g1, bt1, b2, g2, bt2, Wm,
                                            ptsf, roisf, params, flag);
    k_soa<<<16, 256, 0, stream>>>(ptsf, psx, psy, psz);
    k_transpose<<<dim3(NPT / 32, CINF / 32, NB), dim3(32, 8), 0, stream>>>(feat, ftbf, flag);
    k_prep<<<484, 256, 0, stream>>>(Wm, W1, W2, wbf, w1bf, w2bf, stats, flag);
    k_knn2<<<NB * NPT / 4, 256, 0, stream>>>(psx, psy, psz, idxb);
    k_dense<<<dim3(256, 2), 256, 0, stream>>>(ftbf, wbf, Hf);
    k_gather<<<(NB * NPT) / GPTS, 256, 0, stream>>>(Hf, idxb, ptsf, wxyz, Hmax, Hmin, stats);
    k_feats0<<<(NB * NPT * C1) / 256, 256, 0, stream>>>(Hmax, Hmin, stats, params + 0, params + 256, f0bf);
    k_lin<256><<<256, 256, 0, stream>>>(f0bf, w1bf, params + 33280, h1, stats + 512, stats + 640);
    k_bnrelu<<<(NB * NPT * C2) / 256, 256, 0, stream>>>(h1, stats + 512, stats + 640, params + 33408, params + 33536, x1bf);
    k_lin<128><<<256, 256, 0, stream>>>(x1bf, w2bf, params + 50048, h2, stats + 768, stats + 896);
    k_final<<<(NB * NPT * C2) / 256, 256, 0, stream>>>(h2, stats + 768, stats + 896, params + 50176, params + 50304, fp, d_out, flag);
    k_pool<<<NB * NROI, 64, 0, stream>>>(ptsf, roisf, fp, d_out, flag);
}

// Round 9
// 196.096 us; speedup vs baseline: 5.8113x; 1.1497x over previous
//
#include <hip/hip_runtime.h>
#include <hip/hip_bf16.h>

typedef __hip_bfloat16 bf16;
typedef unsigned short u16;

#define NB   2
#define NPT  2048
#define NROI 128
#define CINF 256
#define NS   16
#define KDIM 259     // CIN + 3
#define KP2  288     // W_mlp repack stride (cols 0..255 feat, 256..258 xyz, pad)
#define C1   256     // mlp out channels
#define C2   128     // layer1/2 out channels
#define NVOX 125
#define EPSF 1e-5f

typedef __bf16 bf16x8 __attribute__((ext_vector_type(8)));
typedef float  f32x4  __attribute__((ext_vector_type(4)));

// flag-branched input load: inputs are either all-bf16 or all-f32 (runtime-detected)
__device__ __forceinline__ float ldin(const void* p, size_t i, int f32flag) {
    if (f32flag) return ((const float*)p)[i];
    unsigned short u = ((const unsigned short*)p)[i];
    return __uint_as_float(((unsigned)u) << 16);
}

// round-to-nearest-even f32 -> bf16 (matches numpy)
__device__ __forceinline__ unsigned short f2bf(float x) {
    unsigned u = __float_as_uint(x);
    u += 0x7FFFu + ((u >> 16) & 1u);
    return (unsigned short)(u >> 16);
}

// ---------------- ws layout (float units), total 4,374,544 f = 17.5 MB ----------------
// flag  @0        [16]
// ptsf  @16       [12288]
// roisf @12304    [1792]
// params@14096    [50432]
// Wbf   @64528    [36864]  (256x288 bf16)
// stats @101392   [1024]
// idxb  @102416   [65536 ints]
// ftbf  @167952   [524288] (bf16)  -- f0bf overlays
// Hmax  @1216528  [1048576]  -- h1 overlays; x1bf @1740816
// Hmin  @2265104  [1048576]  -- h2 overlays; fp @2789392
// psx   @3313680  [4096]; psy @3317776 [4096]; psz @3321872 [4096]
// Hf    @3325968  [1048576]  (f32, dead after k_gather; k_pool2 reuses as glist)

// D0: detect input dtype
__global__ void k_detect(const void* __restrict__ Wm, int* __restrict__ flag) {
    __shared__ int f;
    int tid = threadIdx.x;
    if (tid == 0) f = 0;
    __syncthreads();
    #pragma unroll
    for (int r = 0; r < 4; r++) {
        unsigned short u = ((const unsigned short*)Wm)[r * 256 + tid];
        float v = __uint_as_float(((unsigned)u) << 16);
        if (!(fabsf(v) <= 1e4f)) atomicOr(&f, 1);
    }
    __syncthreads();
    if (tid == 0) *flag = f;
}

// D1: convert pts/rois/small params to f32 scratch; case 10 extracts W_xyz [3][256]
__global__ void k_cvt(const void* __restrict__ pts, const void* __restrict__ rois,
                      const void* __restrict__ gm, const void* __restrict__ btm,
                      const void* __restrict__ b1, const void* __restrict__ g1,
                      const void* __restrict__ bt1, const void* __restrict__ b2,
                      const void* __restrict__ g2, const void* __restrict__ bt2,
                      const void* __restrict__ Wm,
                      float* __restrict__ ptsf, float* __restrict__ roisf,
                      float* __restrict__ params, const int* __restrict__ flag) {
    int f = *flag;
    int e = blockIdx.x * 256 + threadIdx.x;
    if (blockIdx.y == 10) {   // wxyz[d*256+o] = Wm[o*KDIM+d]
        if (e < 768) {
            int d = e >> 8, o = e & 255;
            params[25088 + e] = ldin(Wm, (size_t)o * KDIM + d, f);
        }
        return;
    }
    const void* src; float* dst; int n;
    switch (blockIdx.y) {
        case 0:  src = pts; dst = ptsf;           n = NB * NPT * 3; break;
        case 1:  src = rois; dst = roisf;         n = NB * NROI * 7; break;
        case 2:  src = gm;  dst = params + 0;     n = 256; break;
        case 3:  src = btm; dst = params + 256;   n = 256; break;
        case 4:  src = b1;  dst = params + 33280; n = 128; break;
        case 5:  src = g1;  dst = params + 33408; n = 128; break;
        case 6:  src = bt1; dst = params + 33536; n = 128; break;
        case 7:  src = b2;  dst = params + 50048; n = 128; break;
        case 8:  src = g2;  dst = params + 50176; n = 128; break;
        default: src = bt2; dst = params + 50304; n = 128; break;
    }
    if (e < n) dst[e] = ldin(src, e, f);
}

// D2: split points into SoA for the coalesced ballot-scan knn
__global__ void k_soa(const float* __restrict__ ptsf, float* __restrict__ psx,
                      float* __restrict__ psy, float* __restrict__ psz) {
    int e = blockIdx.x * 256 + threadIdx.x;
    if (e < NB * NPT) {
        psx[e] = ptsf[e * 3 + 0];
        psy[e] = ptsf[e * 3 + 1];
        psz[e] = ptsf[e * 3 + 2];
    }
}

// K0a: transpose features (B,CIN,N) -> ftbf (B,N,CIN) bf16
__global__ void k_transpose(const void* __restrict__ feat, u16* __restrict__ ftbf,
                            const int* __restrict__ flag) {
    __shared__ float tile[32][33];
    int f = *flag;
    int b = blockIdx.z;
    int n0 = blockIdx.x * 32, c0 = blockIdx.y * 32;
    int tx = threadIdx.x, ty = threadIdx.y;  // 32x8
    #pragma unroll
    for (int d = 0; d < 4; d++) {
        int c = c0 + ty + d * 8;
        tile[ty + d * 8][tx] = ldin(feat, ((size_t)(b * CINF + c)) * NPT + n0 + tx, f);
    }
    __syncthreads();
    #pragma unroll
    for (int d = 0; d < 4; d++) {
        int n = n0 + ty + d * 8;
        ftbf[((size_t)(b * NPT + n)) * CINF + c0 + tx] = f2bf(tile[tx][ty + d * 8]);
    }
}

// K0b: repack W_mlp -> Wbf [256][288] bf16; zero stats; repack W1/W2 -> bf16
__global__ void k_prep(const void* __restrict__ Wm, const void* __restrict__ W1,
                       const void* __restrict__ W2, u16* __restrict__ wbf,
                       u16* __restrict__ w1bf, u16* __restrict__ w2bf,
                       float* __restrict__ stats, const int* __restrict__ flag) {
    int f = *flag;
    int e = blockIdx.x * 256 + threadIdx.x;
    if (e < 256 * KP2) {
        int o = e / KP2, k = e % KP2;
        float v = 0.f;
        if (k < 256)      v = ldin(Wm, (size_t)o * KDIM + 3 + k, f);
        else if (k < 259) v = ldin(Wm, (size_t)o * KDIM + (k - 256), f);
        wbf[e] = f2bf(v);
    } else if (e < 256 * KP2 + 1024) {
        stats[e - 256 * KP2] = 0.f;
    } else if (e < 256 * KP2 + 1024 + 32768) {
        int idx = e - (256 * KP2 + 1024);
        w1bf[idx] = f2bf(ldin(W1, idx, f));
    } else if (e < 256 * KP2 + 1024 + 32768 + 16384) {
        int idx = e - (256 * KP2 + 1024 + 32768);
        w2bf[idx] = f2bf(ldin(W2, idx, f));
    }
}

// K1: ball query, wave-per-query ballot scan.
__global__ __launch_bounds__(256) void k_knn2(const float* __restrict__ psx, const float* __restrict__ psy,
                                              const float* __restrict__ psz, int* __restrict__ idxb) {
    #pragma clang fp contract(off)
    int wid = threadIdx.x >> 6, lane = threadIdx.x & 63;
    int q = blockIdx.x * 4 + wid;                  // 0..4095
    int b = q >> 11;
    int base = b * NPT;
    float qx = psx[q], qy = psy[q], qz = psz[q];
    const float R2 = (float)(0.3 * 0.3);
    size_t ob = (size_t)q * NS;
    int cnt = 0, j0 = -1;
    unsigned long long below = (lane == 63) ? ~0ull >> 1 : ((1ull << (lane + 1)) - 1) >> 1;
    for (int c0 = 0; c0 < NPT; c0 += 64) {
        int j = c0 + lane;
        float dx = qx - psx[base + j];
        float dy = qy - psy[base + j];
        float dz = qz - psz[base + j];
        float d2 = dx * dx + dy * dy + dz * dz;
        bool hit = d2 < R2;
        unsigned long long m = __ballot(hit);
        if (m) {
            if (j0 < 0) j0 = c0 + __builtin_ctzll(m);
            int pos = cnt + __popcll(m & below);
            if (hit && pos < NS) idxb[ob + pos] = j;
            cnt += __popcll(m);
        }
        if (cnt >= NS) break;
    }
    if (lane >= cnt && lane < NS) idxb[ob + lane] = j0;
}

// K2a (dense MFMA): Hf[4096x256] = ftbf(4096x256) . W_feat^T. Wave = 16 rows x 32 cols.
__global__ __launch_bounds__(256) void k_dense(const u16* __restrict__ ftbf, const u16* __restrict__ wbf,
                                               float* __restrict__ Hf) {
    int w = threadIdx.x >> 6, lane = threadIdx.x & 63;
    int lg = lane >> 4, lr = lane & 15;
    int rbase = blockIdx.x * 16;
    int c0 = blockIdx.y * 128 + w * 32;

    size_t aoff  = (size_t)(rbase + lr) * CINF + lg * 8;
    size_t boff0 = (size_t)(c0 + lr) * KP2 + lg * 8;
    size_t boff1 = (size_t)(c0 + 16 + lr) * KP2 + lg * 8;

    f32x4 acc0 = (f32x4){0.f, 0.f, 0.f, 0.f};
    f32x4 acc1 = (f32x4){0.f, 0.f, 0.f, 0.f};
    #pragma unroll
    for (int k0 = 0; k0 < 256; k0 += 32) {
        bf16x8 af = __builtin_bit_cast(bf16x8, *(const uint4*)(ftbf + aoff + k0));
        bf16x8 b0 = __builtin_bit_cast(bf16x8, *(const uint4*)(wbf + boff0 + k0));
        bf16x8 b1 = __builtin_bit_cast(bf16x8, *(const uint4*)(wbf + boff1 + k0));
        acc0 = __builtin_amdgcn_mfma_f32_16x16x32_bf16(af, b0, acc0, 0, 0, 0);
        acc1 = __builtin_amdgcn_mfma_f32_16x16x32_bf16(af, b1, acc1, 0, 0, 0);
    }
    #pragma unroll
    for (int r = 0; r < 4; r++) {
        int row = rbase + lg * 4 + r;
        Hf[(size_t)row * C1 + c0 + lr] = acc0[r];
        Hf[(size_t)row * C1 + c0 + 16 + lr] = acc1[r];
    }
}

// K2b (gather-reduce): per point, h[s,o] = Hf[j_s][o] + W_xyz[o].gx(s); max/min over s + stats
#define GPTS 8
__global__ __launch_bounds__(256) void k_gather(const float* __restrict__ Hf, const int* __restrict__ idxb,
                                                const float* __restrict__ ptsf, const float* __restrict__ wxyz,
                                                float* __restrict__ Hmax, float* __restrict__ Hmin,
                                                float* __restrict__ stats) {
    __shared__ int   lj[NS];
    __shared__ float lgx[NS], lgy[NS], lgz[NS];
    int o = threadIdx.x;
    float wx = wxyz[o], wy = wxyz[256 + o], wz = wxyz[512 + o];
    float ssum = 0.f, ssq = 0.f;
    for (int p = 0; p < GPTS; p++) {
        int pt = blockIdx.x * GPTS + p;
        int b = pt >> 11;
        int base = b * NPT;
        if (o < NS) {
            int j = idxb[(size_t)pt * NS + o];
            lj[o] = j;
            size_t jb = ((size_t)(base + j)) * 3;
            size_t cb = (size_t)pt * 3;
            lgx[o] = (ptsf[jb]     - ptsf[cb])     / 0.3f;
            lgy[o] = (ptsf[jb + 1] - ptsf[cb + 1]) / 0.3f;
            lgz[o] = (ptsf[jb + 2] - ptsf[cb + 2]) / 0.3f;
        }
        __syncthreads();
        float mx = -3.4e38f, mn = 3.4e38f;
        #pragma unroll
        for (int s = 0; s < NS; s++) {
            float v = Hf[(size_t)(base + lj[s]) * C1 + o] + wx * lgx[s] + wy * lgy[s] + wz * lgz[s];
            mx = fmaxf(mx, v); mn = fminf(mn, v);
            ssum += v; ssq += v * v;
        }
        Hmax[(size_t)pt * C1 + o] = mx;
        Hmin[(size_t)pt * C1 + o] = mn;
        __syncthreads();
    }
    atomicAdd(&stats[o], ssum);
    atomicAdd(&stats[256 + o], ssq);
}

// K4: feats0 = max_s relu(BN(h)) via affine-monotone identity; emit bf16 for MFMA tail
__global__ void k_feats0(const float* __restrict__ Hmax, const float* __restrict__ Hmin,
                         const float* __restrict__ stats, const float* __restrict__ g,
                         const float* __restrict__ bt, u16* __restrict__ f0bf) {
    int e = blockIdx.x * 256 + threadIdx.x;
    if (e >= NB * NPT * C1) return;
    int o = e & (C1 - 1);
    const float inv = 1.f / 65536.f;
    float m = stats[o] * inv;
    float var = fmaxf(stats[256 + o] * inv - m * m, 0.f);
    float a = g[o] / sqrtf(var + EPSF);
    float d = bt[o] - m * a;
    float h = (a > 0.f) ? Hmax[e] : Hmin[e];
    f0bf[e] = f2bf(fmaxf(a * h + d, 0.f));
}

// K5/K7 (MFMA): out(4096xC2) = Xbf(4096xK) . Wb^T(KxC2) + bias, fused BN-stat epilogue.
template<int K>
__global__ __launch_bounds__(256) void k_lin(const u16* __restrict__ Xbf, const u16* __restrict__ Wb,
                                             const float* __restrict__ bias, float* __restrict__ out,
                                             float* __restrict__ sum, float* __restrict__ sumsq) {
    int w = threadIdx.x >> 6, lane = threadIdx.x & 63;
    int lg = lane >> 4, lr = lane & 15;
    int rbase = blockIdx.x * 16;
    int c0 = w * 32;

    size_t aoff = (size_t)(rbase + lr) * K + lg * 8;
    size_t boff0 = (size_t)(c0 + lr) * K + lg * 8;
    size_t boff1 = (size_t)(c0 + 16 + lr) * K + lg * 8;

    f32x4 acc0 = (f32x4){0.f, 0.f, 0.f, 0.f};
    f32x4 acc1 = (f32x4){0.f, 0.f, 0.f, 0.f};
    #pragma unroll
    for (int k0 = 0; k0 < K; k0 += 32) {
        bf16x8 af = __builtin_bit_cast(bf16x8, *(const uint4*)(Xbf + aoff + k0));
        bf16x8 b0 = __builtin_bit_cast(bf16x8, *(const uint4*)(Wb + boff0 + k0));
        bf16x8 b1 = __builtin_bit_cast(bf16x8, *(const uint4*)(Wb + boff1 + k0));
        acc0 = __builtin_amdgcn_mfma_f32_16x16x32_bf16(af, b0, acc0, 0, 0, 0);
        acc1 = __builtin_amdgcn_mfma_f32_16x16x32_bf16(af, b1, acc1, 0, 0, 0);
    }

    #pragma unroll
    for (int ct = 0; ct < 2; ct++) {
        f32x4 a = ct ? acc1 : acc0;
        int col = c0 + ct * 16 + lr;
        float bi = bias[col];
        float s = 0.f, q = 0.f;
        #pragma unroll
        for (int r = 0; r < 4; r++) {
            float h = a[r] + bi;
            out[(size_t)(rbase + lg * 4 + r) * C2 + col] = h;
            s += h; q += h * h;
        }
        s += __shfl_xor(s, 16); s += __shfl_xor(s, 32);
        q += __shfl_xor(q, 16); q += __shfl_xor(q, 32);
        if (lane < 16) {
            atomicAdd(&sum[col], s);
            atomicAdd(&sumsq[col], q);
        }
    }
}

// K6: x = relu(BN(h)) (layer1) -> bf16 for the next MFMA
__global__ void k_bnrelu(const float* __restrict__ h, const float* __restrict__ sum,
                         const float* __restrict__ sumsq, const float* __restrict__ g,
                         const float* __restrict__ bt, u16* __restrict__ xbf) {
    int e = blockIdx.x * 256 + threadIdx.x;
    if (e >= NB * NPT * C2) return;
    int o = e & (C2 - 1);
    const float inv = 1.f / 4096.f;
    float m = sum[o] * inv;
    float var = fmaxf(sumsq[o] * inv - m * m, 0.f);
    float a = g[o] / sqrtf(var + EPSF);
    float d = bt[o] - m * a;
    xbf[e] = f2bf(fmaxf(a * h[e] + d, 0.f));
}

// K8: feats = relu(BN(h2)); write output 0 (B,C2,N) in detected dtype + f32 copy for pooling
__global__ void k_final(const float* __restrict__ h2, const float* __restrict__ sum,
                        const float* __restrict__ sumsq, const float* __restrict__ g,
                        const float* __restrict__ bt, float* __restrict__ fp,
                        void* __restrict__ out0, const int* __restrict__ flag) {
    int e = blockIdx.x * 256 + threadIdx.x;
    if (e >= NB * NPT * C2) return;
    int f = *flag;
    int o = e & (C2 - 1);
    int bn = e >> 7;
    int b = bn >> 11, n = bn & (NPT - 1);
    const float inv = 1.f / 4096.f;
    float m = sum[o] * inv;
    float var = fmaxf(sumsq[o] * inv - m * m, 0.f);
    float a = g[o] / sqrtf(var + EPSF);
    float d = bt[o] - m * a;
    float v = fmaxf(a * h2[e] + d, 0.f);
    fp[e] = v;
    size_t oi = ((size_t)(b * C2 + o)) * NPT + n;
    if (f) ((float*)out0)[oi] = v;
    else   ((unsigned short*)out0)[oi] = f2bf(v);
}

// K9: RoI voxel max-pool, v2. One 512-thr block per (b,r); single 125x128 int-LDS tile.
// feats >= 0 so int-compare == float-compare and init 0 == ref's neginf->0.
// List compaction goes to global scratch (dead Hf region); order irrelevant (max commutes).
__global__ __launch_bounds__(512) void k_pool2(const float* __restrict__ ptsf, const float* __restrict__ roisf,
                                               const float* __restrict__ fp, void* __restrict__ d_out,
                                               const int* __restrict__ flag, int* __restrict__ glist) {
    #pragma clang fp contract(off)
    __shared__ int pooled[NVOX * C2];   // 64000 B
    __shared__ int cnt;
    __shared__ float rp[8];             // cx cy cz hx hy hz cf sf
    int f = *flag;
    int bid = blockIdx.x;
    int b = bid >> 7;
    int tid = threadIdx.x;
    for (int k = tid; k < NVOX * C2; k += 512) pooled[k] = 0;
    if (tid == 0) {
        cnt = 0;
        size_t rb = ((size_t)bid) * 7;
        rp[0] = roisf[rb];     rp[1] = roisf[rb + 1]; rp[2] = roisf[rb + 2];
        rp[3] = roisf[rb + 3] * 0.5f;
        rp[4] = roisf[rb + 4] * 0.5f;
        rp[5] = roisf[rb + 5] * 0.5f;
        float ry = roisf[rb + 6];
        rp[6] = (float)cos((double)ry);
        rp[7] = (float)sin((double)ry);
    }
    __syncthreads();
    float cx = rp[0], cy = rp[1], cz = rp[2];
    float hx = rp[3], hy = rp[4], hz = rp[5];
    float cf = rp[6], sf = rp[7];
    int* mylist = glist + bid * NPT;
    for (int n = tid; n < NPT; n += 512) {
        size_t pb = ((size_t)(b * NPT + n)) * 3;
        float rx  = ptsf[pb]     - cx;
        float ryy = ptsf[pb + 1] - cy;
        float rz  = ptsf[pb + 2] - cz;
        float lx = rx * cf + ryy * sf;
        float ly = -rx * sf + ryy * cf;
        if (fabsf(lx) < hx && fabsf(ly) < hy && fabsf(rz) < hz) {
            int vx = (int)fminf(fmaxf(floorf((lx + hx) / (2.f * hx) * 5.f), 0.f), 4.f);
            int vy = (int)fminf(fmaxf(floorf((ly + hy) / (2.f * hy) * 5.f), 0.f), 4.f);
            int vz = (int)fminf(fmaxf(floorf((rz + hz) / (2.f * hz) * 5.f), 0.f), 4.f);
            int vox = (vx * 5 + vy) * 5 + vz;
            int pos = atomicAdd(&cnt, 1);
            mylist[pos] = (vox << 16) | n;
        }
    }
    __syncthreads();
    int m = cnt;
    int c = tid & 127, slot = tid >> 7;           // 4 entry-slots x 128 channels
    for (int e = slot; e < m; e += 4) {
        int u = mylist[e];
        int n = u & 0xFFFF, vox = u >> 16;
        float v = fp[((size_t)(b * NPT + n)) * C2 + c];
        atomicMax(&pooled[vox * C2 + c], __float_as_int(v));
    }
    __syncthreads();
    size_t ob = (size_t)524288 + (size_t)bid * (NVOX * C2);
    for (int k = tid; k < NVOX * C2; k += 512) {
        float v = __int_as_float(pooled[k]);
        if (f) ((float*)d_out)[ob + k] = v;
        else   ((unsigned short*)d_out)[ob + k] = f2bf(v);
    }
}

extern "C" void kernel_launch(void* const* d_in, const int* in_sizes, int n_in,
                              void* d_out, int out_size, void* d_ws, size_t ws_size,
                              hipStream_t stream) {
    const void* pts  = d_in[0];
    const void* feat = d_in[1];
    const void* rois = d_in[2];
    const void* Wm   = d_in[3];
    const void* gm   = d_in[4];
    const void* btm  = d_in[5];
    const void* W1   = d_in[6];
    const void* b1   = d_in[7];
    const void* g1   = d_in[8];
    const void* bt1  = d_in[9];
    const void* W2   = d_in[10];
    const void* b2   = d_in[11];
    const void* g2   = d_in[12];
    const void* bt2  = d_in[13];

    float* ws     = (float*)d_ws;
    int*   flag   = (int*)ws;                  // @0
    float* ptsf   = ws + 16;
    float* roisf  = ws + 12304;
    float* params = ws + 14096;
    u16*   w1bf   = (u16*)(params + 512);
    u16*   w2bf   = (u16*)(params + 512 + 16384);
    float* wxyz   = params + 25088;            // [3][256] f32
    u16*   wbf    = (u16*)(ws + 64528);        // 256x288 bf16
    float* stats  = ws + 101392;
    int*   idxb   = (int*)(ws + 102416);
    u16*   ftbf   = (u16*)(ws + 167952);       // 2x2048x256 bf16
    float* Hmax   = ws + 1216528;
    float* Hmin   = ws + 2265104;
    u16*   f0bf   = (u16*)(ws + 167952);       // overlays ftbf (dead after k_dense)
    float* h1     = ws + 1216528;              // overlays Hmax (dead after feats0)
    u16*   x1bf   = (u16*)(ws + 1740816);
    float* h2     = ws + 2265104;              // overlays Hmin
    float* fp     = ws + 2789392;
    float* psx    = ws + 3313680;
    float* psy    = ws + 3317776;
    float* psz    = ws + 3321872;
    float* Hf     = ws + 3325968;              // f32 4096x256 (dead after k_gather)
    int*   glist  = (int*)(ws + 3325968);      // overlays Hf: 256 ROIs x 2048 ints

    k_detect<<<1, 256, 0, stream>>>(Wm, flag);
    k_cvt<<<dim3(48, 11), 256, 0, stream>>>(pts, rois, gm, btm, b1, g1, bt1, b2, g2, bt2, Wm,
                                            ptsf, roisf, params, flag);
    k_soa<<<16, 256, 0, stream>>>(ptsf, psx, psy, psz);
    k_transpose<<<dim3(NPT / 32, CINF / 32, NB), dim3(32, 8), 0, stream>>>(feat, ftbf, flag);
    k_prep<<<484, 256, 0, stream>>>(Wm, W1, W2, wbf, w1bf, w2bf, stats, flag);
    k_knn2<<<NB * NPT / 4, 256, 0, stream>>>(psx, psy, psz, idxb);
    k_dense<<<dim3(256, 2), 256, 0, stream>>>(ftbf, wbf, Hf);
    k_gather<<<(NB * NPT) / GPTS, 256, 0, stream>>>(Hf, idxb, ptsf, wxyz, Hmax, Hmin, stats);
    k_feats0<<<(NB * NPT * C1) / 256, 256, 0, stream>>>(Hmax, Hmin, stats, params + 0, params + 256, f0bf);
    k_lin<256><<<256, 256, 0, stream>>>(f0bf, w1bf, params + 33280, h1, stats + 512, stats + 640);
    k_bnrelu<<<(NB * NPT * C2) / 256, 256, 0, stream>>>(h1, stats + 512, stats + 640, params + 33408, params + 33536, x1bf);
    k_lin<128><<<256, 256, 0, stream>>>(x1bf, w2bf, params + 50048, h2, stats + 768, stats + 896);
    k_final<<<(NB * NPT * C2) / 256, 256, 0, stream>>>(h2, stats + 768, stats + 896, params + 50176, params + 50304, fp, d_out, flag);
    k_pool2<<<NB * NROI, 512, 0, stream>>>(ptsf, roisf, fp, d_out, flag, glist);
}

// Round 10
// 181.872 us; speedup vs baseline: 6.2658x; 1.0782x over previous
//
#include <hip/hip_runtime.h>
#include <hip/hip_bf16.h>

typedef __hip_bfloat16 bf16;
typedef unsigned short u16;

#define NB   2
#define NPT  2048
#define NROI 128
#define CINF 256
#define NS   16
#define KDIM 259     // CIN + 3
#define KP2  288     // W_mlp repack stride (cols 0..255 feat, 256..258 xyz, pad)
#define C1   256     // mlp out channels
#define C2   128     // layer1/2 out channels
#define NVOX 125
#define EPSF 1e-5f

typedef __bf16 bf16x8 __attribute__((ext_vector_type(8)));
typedef float  f32x4  __attribute__((ext_vector_type(4)));

// flag-branched input load: inputs are either all-bf16 or all-f32 (runtime-detected)
__device__ __forceinline__ float ldin(const void* p, size_t i, int f32flag) {
    if (f32flag) return ((const float*)p)[i];
    unsigned short u = ((const unsigned short*)p)[i];
    return __uint_as_float(((unsigned)u) << 16);
}

// round-to-nearest-even f32 -> bf16 (matches numpy)
__device__ __forceinline__ unsigned short f2bf(float x) {
    unsigned u = __float_as_uint(x);
    u += 0x7FFFu + ((u >> 16) & 1u);
    return (unsigned short)(u >> 16);
}

// Inline dtype detect: scan first 64 u16 of W_mlp (identical addresses in every
// thread -> broadcast loads, uniform result). True-bf16 weights: |v|<=~0.2 all.
// f32-misread-as-bf16: the 32 low-half words are uniform random 16-bit patterns;
// P(any |v|>1e4 or NaN) = 1 - 0.55^32 ~ 1-5e-9.
__device__ __forceinline__ int detect_flag(const void* __restrict__ Wm) {
    const uint4* p = (const uint4*)Wm;
    int bad = 0;
    #pragma unroll
    for (int i = 0; i < 8; i++) {
        uint4 v = p[i];
        unsigned w[4] = {v.x, v.y, v.z, v.w};
        #pragma unroll
        for (int j = 0; j < 4; j++) {
            if (!(fabsf(__uint_as_float(w[j] << 16)) <= 1e4f)) bad = 1;
            if (!(fabsf(__uint_as_float(w[j] & 0xFFFF0000u)) <= 1e4f)) bad = 1;
        }
    }
    return bad;
}

// ---------------- ws layout (float units), total 4,374,544 f = 17.5 MB ----------------
// (flag slot retired; layout otherwise identical to R9)
// ptsf  @16       [12288]
// roisf @12304    [1792]
// params@14096    [50432]
// Wbf   @64528    [36864]  (256x288 bf16)
// stats @101392   [1024]
// idxb  @102416   [65536 ints]
// ftbf  @167952   [524288] (bf16)
// Hmax  @1216528  [1048576]  -- h1 overlays
// Hmin  @2265104  [1048576]  -- h2 overlays; fp @2789392
// psx   @3313680  [4096]; psy @3317776 [4096]; psz @3321872 [4096]
// Hf    @3325968  [1048576]  (f32, dead after k_gather; k_pool2 reuses as glist)

// K_A: fused setup — transpose + all param repacks/conversions + SoA + stats zero.
// Block ranges: [0,1024) transpose | [1024,1312) wbf | [1312,1440) w1bf |
// [1440,1504) w2bf | [1504,1552) ptsf | [1552,1559) roisf | [1559,1567) small |
// [1567,1570) wxyz | [1570,1586) soa | [1586,1590) stats
__global__ __launch_bounds__(256) void k_setup(
    const void* __restrict__ pts, const void* __restrict__ feat, const void* __restrict__ rois,
    const void* __restrict__ Wm, const void* __restrict__ gm, const void* __restrict__ btm,
    const void* __restrict__ W1, const void* __restrict__ b1, const void* __restrict__ g1,
    const void* __restrict__ bt1, const void* __restrict__ W2, const void* __restrict__ b2,
    const void* __restrict__ g2, const void* __restrict__ bt2,
    float* __restrict__ ptsf, float* __restrict__ roisf, float* __restrict__ params,
    u16* __restrict__ wbf, u16* __restrict__ w1bf, u16* __restrict__ w2bf,
    float* __restrict__ stats, u16* __restrict__ ftbf,
    float* __restrict__ psx, float* __restrict__ psy, float* __restrict__ psz) {
    int f = detect_flag(Wm);
    int bx = blockIdx.x;
    int tid = threadIdx.x;
    if (bx < 1024) {                       // transpose feat (B,CIN,N) -> ftbf (B,N,CIN) bf16
        __shared__ float tile[32][33];
        int b = bx >> 9;
        int r = bx & 511;
        int n0 = (r & 63) * 32, c0 = (r >> 6) * 32;
        int tx = tid & 31, ty = tid >> 5;  // 32x8
        #pragma unroll
        for (int d = 0; d < 4; d++) {
            int c = c0 + ty + d * 8;
            tile[ty + d * 8][tx] = ldin(feat, ((size_t)(b * CINF + c)) * NPT + n0 + tx, f);
        }
        __syncthreads();
        #pragma unroll
        for (int d = 0; d < 4; d++) {
            int n = n0 + ty + d * 8;
            ftbf[((size_t)(b * NPT + n)) * CINF + c0 + tx] = f2bf(tile[tx][ty + d * 8]);
        }
    } else if (bx < 1312) {                // W_mlp -> Wbf [256][288]
        int e = (bx - 1024) * 256 + tid;
        int o = e / KP2, k = e % KP2;
        float v = 0.f;
        if (k < 256)      v = ldin(Wm, (size_t)o * KDIM + 3 + k, f);
        else if (k < 259) v = ldin(Wm, (size_t)o * KDIM + (k - 256), f);
        wbf[e] = f2bf(v);
    } else if (bx < 1440) {                // W1 -> bf16
        int e = (bx - 1312) * 256 + tid;
        w1bf[e] = f2bf(ldin(W1, e, f));
    } else if (bx < 1504) {                // W2 -> bf16
        int e = (bx - 1440) * 256 + tid;
        w2bf[e] = f2bf(ldin(W2, e, f));
    } else if (bx < 1552) {                // points -> f32
        int e = (bx - 1504) * 256 + tid;
        if (e < NB * NPT * 3) ptsf[e] = ldin(pts, e, f);
    } else if (bx < 1559) {                // rois -> f32
        int e = (bx - 1552) * 256 + tid;
        if (e < NB * NROI * 7) roisf[e] = ldin(rois, e, f);
    } else if (bx < 1567) {                // small params
        int t = bx - 1559;
        const void* src; int off, n;
        switch (t) {
            case 0: src = gm;  off = 0;     n = 256; break;
            case 1: src = btm; off = 256;   n = 256; break;
            case 2: src = b1;  off = 33280; n = 128; break;
            case 3: src = g1;  off = 33408; n = 128; break;
            case 4: src = bt1; off = 33536; n = 128; break;
            case 5: src = b2;  off = 50048; n = 128; break;
            case 6: src = g2;  off = 50176; n = 128; break;
            default: src = bt2; off = 50304; n = 128; break;
        }
        if (tid < n) params[off + tid] = ldin(src, tid, f);
    } else if (bx < 1570) {                // wxyz[d*256+o] = Wm[o*KDIM+d]
        int e = (bx - 1567) * 256 + tid;
        if (e < 768) {
            int d = e >> 8, o = e & 255;
            params[25088 + e] = ldin(Wm, (size_t)o * KDIM + d, f);
        }
    } else if (bx < 1586) {                // points SoA
        int e = (bx - 1570) * 256 + tid;
        if (e < NB * NPT) {
            psx[e] = ptsf ? ldin(pts, e * 3 + 0, f) : 0.f;
            psy[e] = ldin(pts, e * 3 + 1, f);
            psz[e] = ldin(pts, e * 3 + 2, f);
        }
    } else {                               // zero stats
        int e = (bx - 1586) * 256 + tid;
        if (e < 1024) stats[e] = 0.f;
    }
}

// K_B: fused ball-query (blocks 0..1023) + dense feature GEMM (blocks 1024..1535)
__global__ __launch_bounds__(256) void k_qd(const float* __restrict__ psx, const float* __restrict__ psy,
                                            const float* __restrict__ psz, int* __restrict__ idxb,
                                            const u16* __restrict__ ftbf, const u16* __restrict__ wbf,
                                            float* __restrict__ Hf) {
    int bx = blockIdx.x;
    if (bx < 1024) {
        #pragma clang fp contract(off)
        int wid = threadIdx.x >> 6, lane = threadIdx.x & 63;
        int q = bx * 4 + wid;
        int b = q >> 11;
        int base = b * NPT;
        float qx = psx[q], qy = psy[q], qz = psz[q];
        const float R2 = (float)(0.3 * 0.3);
        size_t ob = (size_t)q * NS;
        int cnt = 0, j0 = -1;
        unsigned long long below = (lane == 63) ? ~0ull >> 1 : ((1ull << (lane + 1)) - 1) >> 1;
        for (int c0 = 0; c0 < NPT; c0 += 64) {
            int j = c0 + lane;
            float dx = qx - psx[base + j];
            float dy = qy - psy[base + j];
            float dz = qz - psz[base + j];
            float d2 = dx * dx + dy * dy + dz * dz;
            bool hit = d2 < R2;
            unsigned long long m = __ballot(hit);
            if (m) {
                if (j0 < 0) j0 = c0 + __builtin_ctzll(m);
                int pos = cnt + __popcll(m & below);
                if (hit && pos < NS) idxb[ob + pos] = j;
                cnt += __popcll(m);
            }
            if (cnt >= NS) break;
        }
        if (lane >= cnt && lane < NS) idxb[ob + lane] = j0;
    } else {
        int bx2 = bx - 1024;
        int w = threadIdx.x >> 6, lane = threadIdx.x & 63;
        int lg = lane >> 4, lr = lane & 15;
        int rbase = (bx2 & 255) * 16;
        int c0 = (bx2 >> 8) * 128 + w * 32;

        size_t aoff  = (size_t)(rbase + lr) * CINF + lg * 8;
        size_t boff0 = (size_t)(c0 + lr) * KP2 + lg * 8;
        size_t boff1 = (size_t)(c0 + 16 + lr) * KP2 + lg * 8;

        f32x4 acc0 = (f32x4){0.f, 0.f, 0.f, 0.f};
        f32x4 acc1 = (f32x4){0.f, 0.f, 0.f, 0.f};
        #pragma unroll
        for (int k0 = 0; k0 < 256; k0 += 32) {
            bf16x8 af = __builtin_bit_cast(bf16x8, *(const uint4*)(ftbf + aoff + k0));
            bf16x8 b0 = __builtin_bit_cast(bf16x8, *(const uint4*)(wbf + boff0 + k0));
            bf16x8 b1 = __builtin_bit_cast(bf16x8, *(const uint4*)(wbf + boff1 + k0));
            acc0 = __builtin_amdgcn_mfma_f32_16x16x32_bf16(af, b0, acc0, 0, 0, 0);
            acc1 = __builtin_amdgcn_mfma_f32_16x16x32_bf16(af, b1, acc1, 0, 0, 0);
        }
        #pragma unroll
        for (int r = 0; r < 4; r++) {
            int row = rbase + lg * 4 + r;
            Hf[(size_t)row * C1 + c0 + lr] = acc0[r];
            Hf[(size_t)row * C1 + c0 + 16 + lr] = acc1[r];
        }
    }
}

// K_C (gather-reduce): per point, h[s,o] = Hf[j_s][o] + W_xyz[o].gx(s); max/min over s + stats
#define GPTS 8
__global__ __launch_bounds__(256) void k_gather(const float* __restrict__ Hf, const int* __restrict__ idxb,
                                                const float* __restrict__ ptsf, const float* __restrict__ wxyz,
                                                float* __restrict__ Hmax, float* __restrict__ Hmin,
                                                float* __restrict__ stats) {
    __shared__ int   lj[NS];
    __shared__ float lgx[NS], lgy[NS], lgz[NS];
    int o = threadIdx.x;
    float wx = wxyz[o], wy = wxyz[256 + o], wz = wxyz[512 + o];
    float ssum = 0.f, ssq = 0.f;
    for (int p = 0; p < GPTS; p++) {
        int pt = blockIdx.x * GPTS + p;
        int b = pt >> 11;
        int base = b * NPT;
        if (o < NS) {
            int j = idxb[(size_t)pt * NS + o];
            lj[o] = j;
            size_t jb = ((size_t)(base + j)) * 3;
            size_t cb = (size_t)pt * 3;
            lgx[o] = (ptsf[jb]     - ptsf[cb])     / 0.3f;
            lgy[o] = (ptsf[jb + 1] - ptsf[cb + 1]) / 0.3f;
            lgz[o] = (ptsf[jb + 2] - ptsf[cb + 2]) / 0.3f;
        }
        __syncthreads();
        float mx = -3.4e38f, mn = 3.4e38f;
        #pragma unroll
        for (int s = 0; s < NS; s++) {
            float v = Hf[(size_t)(base + lj[s]) * C1 + o] + wx * lgx[s] + wy * lgy[s] + wz * lgz[s];
            mx = fmaxf(mx, v); mn = fminf(mn, v);
            ssum += v; ssq += v * v;
        }
        Hmax[(size_t)pt * C1 + o] = mx;
        Hmin[(size_t)pt * C1 + o] = mn;
        __syncthreads();
    }
    atomicAdd(&stats[o], ssum);
    atomicAdd(&stats[256 + o], ssq);
}

// K_D: layer1 GEMM with fused feats0 prologue.
// Prologue computes the block's own 16x256 bf16 tile of f0 = max_s relu(BN(h))
// from Hmax/Hmin + stats (identical arithmetic to the old k_feats0).
__global__ __launch_bounds__(256) void k_lin1f(const float* __restrict__ Hmax, const float* __restrict__ Hmin,
                                               const float* __restrict__ stats, const float* __restrict__ g,
                                               const float* __restrict__ bt, const u16* __restrict__ Wb,
                                               const float* __restrict__ bias, float* __restrict__ out,
                                               float* __restrict__ sum, float* __restrict__ sumsq) {
    __shared__ __align__(16) u16 xa[16][264];   // pad 264 to spread banks
    int tid = threadIdx.x;
    int rbase = blockIdx.x * 16;
    {
        int c = tid;
        const float inv = 1.f / 65536.f;
        float m = stats[c] * inv;
        float var = fmaxf(stats[256 + c] * inv - m * m, 0.f);
        float a = g[c] / sqrtf(var + EPSF);
        float d = bt[c] - m * a;
        #pragma unroll
        for (int r = 0; r < 16; r++) {
            size_t e = (size_t)(rbase + r) * C1 + c;
            float h = (a > 0.f) ? Hmax[e] : Hmin[e];
            xa[r][c] = f2bf(fmaxf(a * h + d, 0.f));
        }
    }
    __syncthreads();
    int w = tid >> 6, lane = tid & 63;
    int lg = lane >> 4, lr = lane & 15;
    int c0 = w * 32;
    size_t boff0 = (size_t)(c0 + lr) * 256 + lg * 8;
    size_t boff1 = (size_t)(c0 + 16 + lr) * 256 + lg * 8;

    f32x4 acc0 = (f32x4){0.f, 0.f, 0.f, 0.f};
    f32x4 acc1 = (f32x4){0.f, 0.f, 0.f, 0.f};
    #pragma unroll
    for (int k0 = 0; k0 < 256; k0 += 32) {
        bf16x8 af = __builtin_bit_cast(bf16x8, *(const uint4*)&xa[lr][k0 + lg * 8]);
        bf16x8 b0 = __builtin_bit_cast(bf16x8, *(const uint4*)(Wb + boff0 + k0));
        bf16x8 b1 = __builtin_bit_cast(bf16x8, *(const uint4*)(Wb + boff1 + k0));
        acc0 = __builtin_amdgcn_mfma_f32_16x16x32_bf16(af, b0, acc0, 0, 0, 0);
        acc1 = __builtin_amdgcn_mfma_f32_16x16x32_bf16(af, b1, acc1, 0, 0, 0);
    }
    #pragma unroll
    for (int ct = 0; ct < 2; ct++) {
        f32x4 a = ct ? acc1 : acc0;
        int col = c0 + ct * 16 + lr;
        float bi = bias[col];
        float s = 0.f, q = 0.f;
        #pragma unroll
        for (int r = 0; r < 4; r++) {
            float h = a[r] + bi;
            out[(size_t)(rbase + lg * 4 + r) * C2 + col] = h;
            s += h; q += h * h;
        }
        s += __shfl_xor(s, 16); s += __shfl_xor(s, 32);
        q += __shfl_xor(q, 16); q += __shfl_xor(q, 32);
        if (lane < 16) {
            atomicAdd(&sum[col], s);
            atomicAdd(&sumsq[col], q);
        }
    }
}

// K_E: layer2 GEMM with fused bnrelu prologue (x1 tile computed from h1 + layer1 stats).
__global__ __launch_bounds__(256) void k_lin2f(const float* __restrict__ h1, const float* __restrict__ stats1,
                                               const float* __restrict__ g, const float* __restrict__ bt,
                                               const u16* __restrict__ Wb, const float* __restrict__ bias,
                                               float* __restrict__ out, float* __restrict__ sum,
                                               float* __restrict__ sumsq) {
    __shared__ __align__(16) u16 xa[16][136];   // pad 136
    int tid = threadIdx.x;
    int rbase = blockIdx.x * 16;
    {
        int c = tid & 127, half = tid >> 7;
        const float inv = 1.f / 4096.f;
        float m = stats1[c] * inv;
        float var = fmaxf(stats1[128 + c] * inv - m * m, 0.f);
        float a = g[c] / sqrtf(var + EPSF);
        float d = bt[c] - m * a;
        #pragma unroll
        for (int rr = 0; rr < 8; rr++) {
            int r = half * 8 + rr;
            float h = h1[(size_t)(rbase + r) * C2 + c];
            xa[r][c] = f2bf(fmaxf(a * h + d, 0.f));
        }
    }
    __syncthreads();
    int w = tid >> 6, lane = tid & 63;
    int lg = lane >> 4, lr = lane & 15;
    int c0 = w * 32;
    size_t boff0 = (size_t)(c0 + lr) * 128 + lg * 8;
    size_t boff1 = (size_t)(c0 + 16 + lr) * 128 + lg * 8;

    f32x4 acc0 = (f32x4){0.f, 0.f, 0.f, 0.f};
    f32x4 acc1 = (f32x4){0.f, 0.f, 0.f, 0.f};
    #pragma unroll
    for (int k0 = 0; k0 < 128; k0 += 32) {
        bf16x8 af = __builtin_bit_cast(bf16x8, *(const uint4*)&xa[lr][k0 + lg * 8]);
        bf16x8 b0 = __builtin_bit_cast(bf16x8, *(const uint4*)(Wb + boff0 + k0));
        bf16x8 b1 = __builtin_bit_cast(bf16x8, *(const uint4*)(Wb + boff1 + k0));
        acc0 = __builtin_amdgcn_mfma_f32_16x16x32_bf16(af, b0, acc0, 0, 0, 0);
        acc1 = __builtin_amdgcn_mfma_f32_16x16x32_bf16(af, b1, acc1, 0, 0, 0);
    }
    #pragma unroll
    for (int ct = 0; ct < 2; ct++) {
        f32x4 a = ct ? acc1 : acc0;
        int col = c0 + ct * 16 + lr;
        float bi = bias[col];
        float s = 0.f, q = 0.f;
        #pragma unroll
        for (int r = 0; r < 4; r++) {
            float h = a[r] + bi;
            out[(size_t)(rbase + lg * 4 + r) * C2 + col] = h;
            s += h; q += h * h;
        }
        s += __shfl_xor(s, 16); s += __shfl_xor(s, 32);
        q += __shfl_xor(q, 16); q += __shfl_xor(q, 32);
        if (lane < 16) {
            atomicAdd(&sum[col], s);
            atomicAdd(&sumsq[col], q);
        }
    }
}

// K_F: feats = relu(BN(h2)); write output 0 (B,C2,N) in detected dtype + f32 copy for pooling
__global__ void k_final(const float* __restrict__ h2, const float* __restrict__ sum,
                        const float* __restrict__ sumsq, const float* __restrict__ g,
                        const float* __restrict__ bt, float* __restrict__ fp,
                        void* __restrict__ out0, const void* __restrict__ Wm) {
    int e = blockIdx.x * 256 + threadIdx.x;
    if (e >= NB * NPT * C2) return;
    int f = detect_flag(Wm);
    int o = e & (C2 - 1);
    int bn = e >> 7;
    int b = bn >> 11, n = bn & (NPT - 1);
    const float inv = 1.f / 4096.f;
    float m = sum[o] * inv;
    float var = fmaxf(sumsq[o] * inv - m * m, 0.f);
    float a = g[o] / sqrtf(var + EPSF);
    float d = bt[o] - m * a;
    float v = fmaxf(a * h2[e] + d, 0.f);
    fp[e] = v;
    size_t oi = ((size_t)(b * C2 + o)) * NPT + n;
    if (f) ((float*)out0)[oi] = v;
    else   ((unsigned short*)out0)[oi] = f2bf(v);
}

// K_G: RoI voxel max-pool. 512-thr block per (b,r); single 125x128 int-LDS tile.
__global__ __launch_bounds__(512) void k_pool2(const float* __restrict__ ptsf, const float* __restrict__ roisf,
                                               const float* __restrict__ fp, void* __restrict__ d_out,
                                               const void* __restrict__ Wm, int* __restrict__ glist) {
    #pragma clang fp contract(off)
    __shared__ int pooled[NVOX * C2];   // 64000 B
    __shared__ int cnt;
    __shared__ float rp[8];             // cx cy cz hx hy hz cf sf
    int f = detect_flag(Wm);
    int bid = blockIdx.x;
    int b = bid >> 7;
    int tid = threadIdx.x;
    for (int k = tid; k < NVOX * C2; k += 512) pooled[k] = 0;
    if (tid == 0) {
        cnt = 0;
        size_t rb = ((size_t)bid) * 7;
        rp[0] = roisf[rb];     rp[1] = roisf[rb + 1]; rp[2] = roisf[rb + 2];
        rp[3] = roisf[rb + 3] * 0.5f;
        rp[4] = roisf[rb + 4] * 0.5f;
        rp[5] = roisf[rb + 5] * 0.5f;
        float ry = roisf[rb + 6];
        rp[6] = (float)cos((double)ry);
        rp[7] = (float)sin((double)ry);
    }
    __syncthreads();
    float cx = rp[0], cy = rp[1], cz = rp[2];
    float hx = rp[3], hy = rp[4], hz = rp[5];
    float cf = rp[6], sf = rp[7];
    int* mylist = glist + bid * NPT;
    for (int n = tid; n < NPT; n += 512) {
        size_t pb = ((size_t)(b * NPT + n)) * 3;
        float rx  = ptsf[pb]     - cx;
        float ryy = ptsf[pb + 1] - cy;
        float rz  = ptsf[pb + 2] - cz;
        float lx = rx * cf + ryy * sf;
        float ly = -rx * sf + ryy * cf;
        if (fabsf(lx) < hx && fabsf(ly) < hy && fabsf(rz) < hz) {
            int vx = (int)fminf(fmaxf(floorf((lx + hx) / (2.f * hx) * 5.f), 0.f), 4.f);
            int vy = (int)fminf(fmaxf(floorf((ly + hy) / (2.f * hy) * 5.f), 0.f), 4.f);
            int vz = (int)fminf(fmaxf(floorf((rz + hz) / (2.f * hz) * 5.f), 0.f), 4.f);
            int vox = (vx * 5 + vy) * 5 + vz;
            int pos = atomicAdd(&cnt, 1);
            mylist[pos] = (vox << 16) | n;
        }
    }
    __syncthreads();
    int m = cnt;
    int c = tid & 127, slot = tid >> 7;           // 4 entry-slots x 128 channels
    for (int e = slot; e < m; e += 4) {
        int u = mylist[e];
        int n = u & 0xFFFF, vox = u >> 16;
        float v = fp[((size_t)(b * NPT + n)) * C2 + c];
        atomicMax(&pooled[vox * C2 + c], __float_as_int(v));
    }
    __syncthreads();
    size_t ob = (size_t)524288 + (size_t)bid * (NVOX * C2);
    for (int k = tid; k < NVOX * C2; k += 512) {
        float v = __int_as_float(pooled[k]);
        if (f) ((float*)d_out)[ob + k] = v;
        else   ((unsigned short*)d_out)[ob + k] = f2bf(v);
    }
}

extern "C" void kernel_launch(void* const* d_in, const int* in_sizes, int n_in,
                              void* d_out, int out_size, void* d_ws, size_t ws_size,
                              hipStream_t stream) {
    const void* pts  = d_in[0];
    const void* feat = d_in[1];
    const void* rois = d_in[2];
    const void* Wm   = d_in[3];
    const void* gm   = d_in[4];
    const void* btm  = d_in[5];
    const void* W1   = d_in[6];
    const void* b1   = d_in[7];
    const void* g1   = d_in[8];
    const void* bt1  = d_in[9];
    const void* W2   = d_in[10];
    const void* b2   = d_in[11];
    const void* g2   = d_in[12];
    const void* bt2  = d_in[13];

    float* ws     = (float*)d_ws;
    float* ptsf   = ws + 16;
    float* roisf  = ws + 12304;
    float* params = ws + 14096;
    u16*   w1bf   = (u16*)(params + 512);
    u16*   w2bf   = (u16*)(params + 512 + 16384);
    float* wxyz   = params + 25088;            // [3][256] f32
    u16*   wbf    = (u16*)(ws + 64528);        // 256x288 bf16
    float* stats  = ws + 101392;
    int*   idxb   = (int*)(ws + 102416);
    u16*   ftbf   = (u16*)(ws + 167952);       // 2x2048x256 bf16
    float* Hmax   = ws + 1216528;
    float* Hmin   = ws + 2265104;
    float* h1     = ws + 1216528;              // overlays Hmax (dead after k_lin1f)
    float* h2     = ws + 2265104;              // overlays Hmin
    float* fp     = ws + 2789392;
    float* psx    = ws + 3313680;
    float* psy    = ws + 3317776;
    float* psz    = ws + 3321872;
    float* Hf     = ws + 3325968;              // f32 4096x256 (dead after k_gather)
    int*   glist  = (int*)(ws + 3325968);      // overlays Hf: 256 ROIs x 2048 ints

    k_setup<<<1590, 256, 0, stream>>>(pts, feat, rois, Wm, gm, btm, W1, b1, g1, bt1,
                                      W2, b2, g2, bt2, ptsf, roisf, params,
                                      wbf, w1bf, w2bf, stats, ftbf, psx, psy, psz);
    k_qd<<<1536, 256, 0, stream>>>(psx, psy, psz, idxb, ftbf, wbf, Hf);
    k_gather<<<(NB * NPT) / GPTS, 256, 0, stream>>>(Hf, idxb, ptsf, wxyz, Hmax, Hmin, stats);
    k_lin1f<<<256, 256, 0, stream>>>(Hmax, Hmin, stats, params + 0, params + 256,
                                     w1bf, params + 33280, h1, stats + 512, stats + 640);
    k_lin2f<<<256, 256, 0, stream>>>(h1, stats + 512, params + 33408, params + 33536,
                                     w2bf, params + 50048, h2, stats + 768, stats + 896);
    k_final<<<(NB * NPT * C2) / 256, 256, 0, stream>>>(h2, stats + 768, stats + 896,
                                                       params + 50176, params + 50304, fp, d_out, Wm);
    k_pool2<<<NB * NROI, 512, 0, stream>>>(ptsf, roisf, fp, d_out, Wm, glist);
}